// Round 10
// baseline (653.122 us; speedup 1.0000x reference)
//
#include <hip/hip_runtime.h>
#include <hip/hip_bf16.h>
#include <stdint.h>

// Transformer decoder layer: B=256, Sd=64, Se=512, D=512, H=8, HD=64, FF=2048.
// f32 in/out; internal compute bf16 MFMA (tolerance is 2% of ref absmax).

#define SDEC 64
#define SENC 512
#define DMODEL 512
#define FFDIM 2048

typedef __bf16 bf16x8 __attribute__((ext_vector_type(8)));
typedef float  f32x4  __attribute__((ext_vector_type(4)));

static __device__ __forceinline__ float bf2f(unsigned short u) {
  union { unsigned int i; float f; } w; w.i = ((unsigned int)u) << 16; return w.f;
}
static __device__ __forceinline__ unsigned short f2bf(float f) {
  union { float f; unsigned int i; } w; w.f = f;
  unsigned int u = w.i;
  return (unsigned short)((u + 0x7fffu + ((u >> 16) & 1u)) >> 16);  // RTNE
}

// Async global->LDS, 16B per lane. LDS dest = wave-uniform base + lane*16.
static __device__ __forceinline__ void gl_lds16(const unsigned short* g, unsigned short* l) {
  __builtin_amdgcn_global_load_lds(
      (const __attribute__((address_space(1))) unsigned int*)g,
      (__attribute__((address_space(3))) unsigned int*)l,
      16, 0, 0);
}

// ---------------------------------------------------------------------------
// f32 -> bf16 elementwise convert (RTNE), 8 elems/thread/iter, grid-stride.
// ---------------------------------------------------------------------------
__global__ __launch_bounds__(256)
void cvt_f32_bf16(const float* __restrict__ in, unsigned short* __restrict__ out, size_t n8)
{
  size_t i = (size_t)blockIdx.x * blockDim.x + threadIdx.x;
  const size_t stride = (size_t)gridDim.x * blockDim.x;
  for (; i < n8; i += stride) {
    const float* p = in + i * 8;
    float4 a = *(const float4*)p, b = *(const float4*)(p + 4);
    union { unsigned short s[8]; uint4 v; } u;
    u.s[0] = f2bf(a.x); u.s[1] = f2bf(a.y); u.s[2] = f2bf(a.z); u.s[3] = f2bf(a.w);
    u.s[4] = f2bf(b.x); u.s[5] = f2bf(b.y); u.s[6] = f2bf(b.z); u.s[7] = f2bf(b.w);
    *(uint4*)(out + i * 8) = u.v;
  }
}

// ---------------------------------------------------------------------------
// Shared fragment-compute over one 32-wide LDS sub-panel pair (R8 layout).
// fsw = swizzled chunk offset (R8-proven zero-conflict pattern).
// ---------------------------------------------------------------------------
#define GEMM_COMPUTE(asrc, bsrc)                                                     \
  {                                                                                  \
    const unsigned short* as_ = (asrc);                                              \
    const unsigned short* bs_ = (bsrc);                                              \
    bf16x8 af[4], bfr[4];                                                            \
    _Pragma("unroll")                                                                \
    for (int mi = 0; mi < 4; ++mi)                                                   \
      af[mi] = *(const bf16x8*)&as_[(wm * 64 + mi * 16 + fr) * 32 + fsw];            \
    _Pragma("unroll")                                                                \
    for (int ni = 0; ni < 4; ++ni)                                                   \
      bfr[ni] = *(const bf16x8*)&bs_[(wn * 64 + ni * 16 + fr) * 32 + fsw];           \
    _Pragma("unroll")                                                                \
    for (int mi = 0; mi < 4; ++mi)                                                   \
      _Pragma("unroll")                                                              \
      for (int ni = 0; ni < 4; ++ni)                                                 \
        acc[mi][ni] = __builtin_amdgcn_mfma_f32_16x16x32_bf16(af[mi], bfr[ni],       \
                                                              acc[mi][ni], 0, 0, 0); \
  }

// Epilogue: LDS-staged, swizzled (phys col = c ^ (fq<<4); R6-verified free).
#define GEMM_EPILOGUE(RELU_)                                                          \
  {                                                                                   \
    const int fq = lane >> 4;                                                         \
    _Pragma("unroll")                                                                 \
    for (int ni = 0; ni < 4; ++ni) {                                                  \
      const int c = wn * 64 + ni * 16 + fr;                                           \
      const float bv = bias ? bias[col0 + c] : 0.f;                                   \
      _Pragma("unroll")                                                               \
      for (int mi = 0; mi < 4; ++mi) {                                                \
        _Pragma("unroll")                                                             \
        for (int t = 0; t < 4; ++t) {                                                 \
          const int r = wm * 64 + mi * 16 + fq * 4 + t;                               \
          float v = acc[mi][ni][t] + bv;                                              \
          if (RELU_) v = fmaxf(v, 0.f);                                               \
          sh[r * 128 + (c ^ (fq << 4))] = f2bf(v);                                    \
        }                                                                             \
      }                                                                               \
    }                                                                                 \
    __syncthreads();                                                                  \
    const int rr = tid >> 4;                                                          \
    const int cc = (tid & 15) * 8;                                                    \
    _Pragma("unroll")                                                                 \
    for (int p = 0; p < 8; ++p) {                                                     \
      const int r = p * 16 + rr;                                                      \
      *(uint4*)(C + (size_t)(row0 + r) * N + col0 + cc) =                             \
          *(const uint4*)&sh[r * 128 + (cc ^ (w << 4))];                              \
    }                                                                                 \
  }

// ---------------------------------------------------------------------------
// 128x128 GEMM, BK=32 (R8-proven: 2-buf dbuf, gl_lds w=16, counted vmcnt(4),
// raw s_barrier, zero-conflict both-sides swizzle, swizzled epilogue).
// Used for the N=512 mid-size GEMMs (in-run control group).
// ---------------------------------------------------------------------------
template<int RELU>
__global__ __launch_bounds__(256, 2)
void gemm_kernel(const unsigned short* __restrict__ A, const unsigned short* __restrict__ Bt,
                 const float* __restrict__ bias, unsigned short* __restrict__ C,
                 int M, int N, int K)
{
  __shared__ unsigned short sh[2 * 8192];   // 2 bufs x (A 8KB | B 8KB) = 32 KB
  const int tid = threadIdx.x;

  const int gx   = gridDim.x;
  const int nwg  = gx * gridDim.y;
  const int orig = blockIdx.y * gx + blockIdx.x;
  const int wg   = (orig & 7) * (nwg >> 3) + (orig >> 3);
  const int row0 = (wg / gx) * 128;
  const int col0 = (wg % gx) * 128;

  const int w = tid >> 6, lane = tid & 63;
  const int wm = w >> 1, wn = w & 1;
  const int gr = lane >> 2;
  const int gc = ((lane & 3) ^ ((lane >> 3) & 3)) * 8;   // pre-swizzled global chunk

  auto STAGE = [&](int k0, int buf) {
    unsigned short* as = sh + buf * 8192;
    unsigned short* bs = as + 4096;
    #pragma unroll
    for (int i = 0; i < 2; ++i) {
      const int rbase = w * 32 + i * 16;   // wave-uniform, % 16 == 0
      gl_lds16(A  + (size_t)(row0 + rbase + gr) * K + (k0 + gc), as + rbase * 32);
      gl_lds16(Bt + (size_t)(col0 + rbase + gr) * K + (k0 + gc), bs + rbase * 32);
    }
  };

  f32x4 acc[4][4];
  #pragma unroll
  for (int i = 0; i < 4; ++i)
    #pragma unroll
    for (int j = 0; j < 4; ++j)
      acc[i][j] = (f32x4){0.f, 0.f, 0.f, 0.f};

  const int fr  = lane & 15;
  const int fg  = lane >> 4;
  const int fsw = (fg ^ ((fr >> 1) & 3)) * 8;   // swizzled fragment chunk offset

  STAGE(0, 0);
  int cur = 0;
  for (int k0 = 0; k0 + 32 < K; k0 += 32) {
    STAGE(k0 + 32, cur ^ 1);                          // prefetch next tile
    asm volatile("s_waitcnt vmcnt(4)" ::: "memory");  // own tile's loads done
    __builtin_amdgcn_s_barrier();                     // all waves: tile visible
    asm volatile("" ::: "memory");
    GEMM_COMPUTE(sh + cur * 8192, sh + cur * 8192 + 4096);
    asm volatile("" ::: "memory");
    __builtin_amdgcn_s_barrier();                     // reads of buf[cur] done
    cur ^= 1;
  }
  asm volatile("s_waitcnt vmcnt(0)" ::: "memory");
  __builtin_amdgcn_s_barrier();
  asm volatile("" ::: "memory");
  GEMM_COMPUTE(sh + cur * 8192, sh + cur * 8192 + 4096);
  asm volatile("" ::: "memory");
  __builtin_amdgcn_s_barrier();   // LDS free for epilogue reuse

  GEMM_EPILOGUE(RELU);
}

// ---------------------------------------------------------------------------
// 128x128 GEMM, BK=64: two stacked 32-wide sub-panels per tile (each with the
// EXACT R8 zero-conflict LDS layout), 64 KB LDS (2 bufs), 2 blocks/CU.
// 2 raw barriers per 32 MFMAs (half the R8 barrier frequency), counted
// s_waitcnt vmcnt(8) (8 gl_lds per wave per tile stay in flight).
// Requires K % 64 == 0. Same epilogue. A/B experiment vs gemm_kernel.
// ---------------------------------------------------------------------------
template<int RELU>
__global__ __launch_bounds__(256, 2)
void gemm_bk64_kernel(const unsigned short* __restrict__ A, const unsigned short* __restrict__ Bt,
                      const float* __restrict__ bias, unsigned short* __restrict__ C,
                      int M, int N, int K)
{
  __shared__ unsigned short sh[2 * 16384];   // 2 bufs x (A 16KB | B 16KB) = 64 KB
  const int tid = threadIdx.x;

  const int gx   = gridDim.x;
  const int nwg  = gx * gridDim.y;
  const int orig = blockIdx.y * gx + blockIdx.x;
  const int wg   = (orig & 7) * (nwg >> 3) + (orig >> 3);
  const int row0 = (wg / gx) * 128;
  const int col0 = (wg % gx) * 128;

  const int w = tid >> 6, lane = tid & 63;
  const int wm = w >> 1, wn = w & 1;
  const int gr = lane >> 2;
  const int gc = ((lane & 3) ^ ((lane >> 3) & 3)) * 8;   // pre-swizzled global chunk

  // stage one BK=64 tile as two 32-wide sub-panels (s = 0,1), R8 layout each
  auto STAGE = [&](int k0, int buf) {
    unsigned short* as = sh + buf * 16384;
    unsigned short* bs = as + 8192;
    #pragma unroll
    for (int s = 0; s < 2; ++s) {
      #pragma unroll
      for (int i = 0; i < 2; ++i) {
        const int rbase = w * 32 + i * 16;   // wave-uniform, % 16 == 0
        gl_lds16(A  + (size_t)(row0 + rbase + gr) * K + (k0 + s * 32 + gc),
                 as + s * 4096 + rbase * 32);
        gl_lds16(Bt + (size_t)(col0 + rbase + gr) * K + (k0 + s * 32 + gc),
                 bs + s * 4096 + rbase * 32);
      }
    }
  };

  f32x4 acc[4][4];
  #pragma unroll
  for (int i = 0; i < 4; ++i)
    #pragma unroll
    for (int j = 0; j < 4; ++j)
      acc[i][j] = (f32x4){0.f, 0.f, 0.f, 0.f};

  const int fr  = lane & 15;
  const int fg  = lane >> 4;
  const int fsw = (fg ^ ((fr >> 1) & 3)) * 8;   // R8 swizzled fragment chunk

  const int NT = K >> 6;   // K % 64 == 0
  STAGE(0, 0);
  int cur = 0;
  for (int t = 0; t < NT; ++t) {
    if (t + 1 < NT) {
      STAGE((t + 1) << 6, cur ^ 1);                     // prefetch next tile
      asm volatile("s_waitcnt vmcnt(8)" ::: "memory");  // own tile's 8 loads done
    } else {
      asm volatile("s_waitcnt vmcnt(0)" ::: "memory");
    }
    __builtin_amdgcn_s_barrier();                       // all waves: tile visible
    asm volatile("" ::: "memory");
    {
      const unsigned short* as = sh + cur * 16384;
      const unsigned short* bs = as + 8192;
      GEMM_COMPUTE(as, bs);                             // k sub-panel 0
      GEMM_COMPUTE(as + 4096, bs + 4096);               // k sub-panel 1
    }
    asm volatile("" ::: "memory");
    __builtin_amdgcn_s_barrier();                       // reads of buf[cur] done
    cur ^= 1;
  }

  GEMM_EPILOGUE(RELU);
}

// ---------------------------------------------------------------------------
// MFMA flash attention. One block (4 waves) per (b,h). 64 query rows, HD=64.
// XCD-chunked swizzle so same-b blocks share an XCD's L2 (KV + mask reuse).
// ---------------------------------------------------------------------------
__global__ __launch_bounds__(256, 2)
void attn_mfma(const unsigned short* __restrict__ qbuf, int qstride, int qmul,
               const unsigned short* __restrict__ kvbuf, int kvstride, int kmul, int kadd,
               int tokmul, int Skv, const float* __restrict__ mask,
               unsigned short* __restrict__ vals, float scale)
{
  __shared__ unsigned short Qs[64 * 72];   // pad 72 shorts: 144B rows, 16B-aligned
  __shared__ unsigned short Ks[64 * 72];
  __shared__ unsigned short Vt[64 * 72];   // [d][j] (transposed V tile)
  __shared__ unsigned short Ps[64 * 72];   // [row][j], wave-private 16-row slabs

  const int nwg  = gridDim.x * gridDim.y;          // 8 * B, % 8 == 0
  const int orig = blockIdx.y * gridDim.x + blockIdx.x;
  const int wg   = (orig & 7) * (nwg >> 3) + (orig >> 3);
  const int h = wg & 7, b = wg >> 3;

  const int tid = threadIdx.x;
  const int w = tid >> 6, lane = tid & 63;
  const int srow = tid >> 2;          // 0..63 staging row (token)
  const int sc0 = (tid & 3) * 16;     // 0,16,32,48 staging col (d)

  // stage Q once
  {
    const unsigned short* qg = qbuf + (size_t)(b * 64 + srow) * qstride + h * qmul + sc0;
    *(uint4*)&Qs[srow * 72 + sc0]     = *(const uint4*)qg;
    *(uint4*)&Qs[srow * 72 + sc0 + 8] = *(const uint4*)(qg + 8);
  }

  const int fr = lane & 15;    // A/B frag row index
  const int fg = lane >> 4;    // frag k-group
  const int orow = fg * 4;     // C/D row base within 16-slice

  float mstate[4], lstate[4];
  f32x4 oacc[4];
  #pragma unroll
  for (int t = 0; t < 4; ++t) { mstate[t] = -1e30f; lstate[t] = 0.f; }
  #pragma unroll
  for (int ni = 0; ni < 4; ++ni) oacc[ni] = (f32x4){0.f, 0.f, 0.f, 0.f};

  for (int j0 = 0; j0 < Skv; j0 += 64) {
    __syncthreads();  // prior tile's K/V reads complete (covers Q on iter 0)
    {
      const unsigned short* kg = kvbuf + (size_t)(b * tokmul + j0 + srow) * kvstride
                                 + h * kmul + kadd + sc0;
      *(uint4*)&Ks[srow * 72 + sc0]     = *(const uint4*)kg;
      *(uint4*)&Ks[srow * 72 + sc0 + 8] = *(const uint4*)(kg + 8);
      const unsigned short* vg = kg + 64;  // V sits 64 shorts after K
      uint4 v0 = *(const uint4*)vg;
      uint4 v1 = *(const uint4*)(vg + 8);
      const unsigned short* vsp = (const unsigned short*)&v0;
      #pragma unroll
      for (int jj = 0; jj < 8; ++jj) Vt[(sc0 + jj) * 72 + srow] = vsp[jj];
      vsp = (const unsigned short*)&v1;
      #pragma unroll
      for (int jj = 0; jj < 8; ++jj) Vt[(sc0 + 8 + jj) * 72 + srow] = vsp[jj];
    }
    __syncthreads();

    // S = Q @ K^T  (wave's 16-row slice x 64 key cols)
    f32x4 s[4];
    #pragma unroll
    for (int ni = 0; ni < 4; ++ni) s[ni] = (f32x4){0.f, 0.f, 0.f, 0.f};
    #pragma unroll
    for (int ks = 0; ks < 2; ++ks) {
      bf16x8 aq = *(const bf16x8*)&Qs[(w * 16 + fr) * 72 + ks * 32 + fg * 8];
      #pragma unroll
      for (int ni = 0; ni < 4; ++ni) {
        bf16x8 bk = *(const bf16x8*)&Ks[(ni * 16 + fr) * 72 + ks * 32 + fg * 8];
        s[ni] = __builtin_amdgcn_mfma_f32_16x16x32_bf16(aq, bk, s[ni], 0, 0, 0);
      }
    }

    // online softmax (each lane owns rows orow..orow+3 of the wave slice)
    #pragma unroll
    for (int t = 0; t < 4; ++t) {
      const int grow = w * 16 + orow + t;
      const float* mrow = mask + ((size_t)b * 64 + grow) * Skv + j0;
      float sv[4];
      float tmax = -1e30f;
      #pragma unroll
      for (int ni = 0; ni < 4; ++ni) {
        sv[ni] = s[ni][t] * scale + mrow[ni * 16 + fr];
        tmax = fmaxf(tmax, sv[ni]);
      }
      #pragma unroll
      for (int off = 1; off < 16; off <<= 1) tmax = fmaxf(tmax, __shfl_xor(tmax, off));
      const float mn = fmaxf(mstate[t], tmax);
      const float fscl = __expf(mstate[t] - mn);
      mstate[t] = mn;
      float psum = 0.f;
      #pragma unroll
      for (int ni = 0; ni < 4; ++ni) {
        float p = __expf(sv[ni] - mn);
        psum += p;
        Ps[grow * 72 + ni * 16 + fr] = f2bf(p);
      }
      #pragma unroll
      for (int off = 1; off < 16; off <<= 1) psum += __shfl_xor(psum, off);
      lstate[t] = lstate[t] * fscl + psum;
      #pragma unroll
      for (int ni = 0; ni < 4; ++ni) oacc[ni][t] *= fscl;
    }
    __syncthreads();  // Ps visible (cross-lane), Vt/Ks stable

    // O += P @ V   (A = P rows, B = Vt rows)
    #pragma unroll
    for (int ks = 0; ks < 2; ++ks) {
      bf16x8 pa = *(const bf16x8*)&Ps[(w * 16 + fr) * 72 + ks * 32 + fg * 8];
      #pragma unroll
      for (int ni = 0; ni < 4; ++ni) {
        bf16x8 vb = *(const bf16x8*)&Vt[(ni * 16 + fr) * 72 + ks * 32 + fg * 8];
        oacc[ni] = __builtin_amdgcn_mfma_f32_16x16x32_bf16(pa, vb, oacc[ni], 0, 0, 0);
      }
    }
  }

  // epilogue: normalize, write head block
  #pragma unroll
  for (int t = 0; t < 4; ++t) {
    const int grow = w * 16 + orow + t;
    const float inv = 1.f / lstate[t];
    unsigned short* og = vals + (size_t)(b * 64 + grow) * DMODEL + h * 64;
    #pragma unroll
    for (int ni = 0; ni < 4; ++ni)
      og[ni * 16 + fr] = f2bf(oacc[ni][t] * inv);
  }
}

// ---------------------------------------------------------------------------
// LayerNorm over D=512 with fused residual add. One wave per row, 8 elems/lane.
// proj input is bf16. resid32 XOR resid16 non-null; out16 and/or out32.
// ---------------------------------------------------------------------------
__global__ __launch_bounds__(256)
void ln_kernel(const unsigned short* __restrict__ proj16, const float* __restrict__ resid32,
               const unsigned short* __restrict__ resid16,
               const float* __restrict__ gamma, const float* __restrict__ beta,
               unsigned short* __restrict__ out16, float* __restrict__ out32)
{
  const int w = threadIdx.x >> 6, lane = threadIdx.x & 63;
  const size_t r = (size_t)blockIdx.x * 4 + w;
  const int d0 = lane * 8;

  float x[8];
  {
    uint4 u = *(const uint4*)(proj16 + r * DMODEL + d0);
    const unsigned short* s = (const unsigned short*)&u;
    #pragma unroll
    for (int j = 0; j < 8; ++j) x[j] = bf2f(s[j]);
  }
  if (resid32) {
    const float* p = resid32 + r * DMODEL + d0;
    float4 a = *(const float4*)p, b = *(const float4*)(p + 4);
    x[0] += a.x; x[1] += a.y; x[2] += a.z; x[3] += a.w;
    x[4] += b.x; x[5] += b.y; x[6] += b.z; x[7] += b.w;
  } else {
    uint4 u = *(const uint4*)(resid16 + r * DMODEL + d0);
    const unsigned short* s = (const unsigned short*)&u;
    #pragma unroll
    for (int j = 0; j < 8; ++j) x[j] += bf2f(s[j]);
  }

  float sum = 0.f;
  #pragma unroll
  for (int j = 0; j < 8; ++j) sum += x[j];
  #pragma unroll
  for (int off = 32; off > 0; off >>= 1) sum += __shfl_xor(sum, off);
  const float mean = sum * (1.f / DMODEL);

  float vs = 0.f;
  #pragma unroll
  for (int j = 0; j < 8; ++j) { float t = x[j] - mean; vs += t * t; }
  #pragma unroll
  for (int off = 32; off > 0; off >>= 1) vs += __shfl_xor(vs, off);
  const float rstd = rsqrtf(vs * (1.f / DMODEL) + 1e-5f);

  float4 g0 = *(const float4*)(gamma + d0), g1 = *(const float4*)(gamma + d0 + 4);
  float4 b0 = *(const float4*)(beta + d0),  b1 = *(const float4*)(beta + d0 + 4);
  const float g[8]  = {g0.x, g0.y, g0.z, g0.w, g1.x, g1.y, g1.z, g1.w};
  const float bb[8] = {b0.x, b0.y, b0.z, b0.w, b1.x, b1.y, b1.z, b1.w};
  float y[8];
  #pragma unroll
  for (int j = 0; j < 8; ++j) y[j] = g[j] * (x[j] - mean) * rstd + bb[j];

  if (out16) {
    union { unsigned short s[8]; uint4 v; } p;
    #pragma unroll
    for (int j = 0; j < 8; ++j) p.s[j] = f2bf(y[j]);
    *(uint4*)(out16 + r * DMODEL + d0) = p.v;
  }
  if (out32) {
    float* o = out32 + r * DMODEL + d0;
    *(float4*)o       = (float4){y[0], y[1], y[2], y[3]};
    *(float4*)(o + 4) = (float4){y[4], y[5], y[6], y[7]};
  }
}

// ---------------------------------------------------------------------------
// Transpose + f32->bf16 convert: W[K,N] f32 -> Wt[N,K] bf16. 32x32 LDS tiles.
// ---------------------------------------------------------------------------
__global__ __launch_bounds__(256)
void transpose_cvt(const float* __restrict__ W, unsigned short* __restrict__ Wt,
                   int K, int N)
{
  __shared__ float tile[32][33];
  const int tx = threadIdx.x, ty = threadIdx.y;
  const int n = blockIdx.x * 32 + tx;
  #pragma unroll
  for (int rr = 0; rr < 4; ++rr) {
    const int k = blockIdx.y * 32 + ty + rr * 8;
    tile[ty + rr * 8][tx] = W[(size_t)k * N + n];
  }
  __syncthreads();
  const int k2 = blockIdx.y * 32 + tx;
  #pragma unroll
  for (int rr = 0; rr < 4; ++rr) {
    const int n2 = blockIdx.x * 32 + ty + rr * 8;
    Wt[(size_t)n2 * K + k2] = f2bf(tile[tx][ty + rr * 8]);
  }
}

// ---------------------------------------------------------------------------
extern "C" void kernel_launch(void* const* d_in, const int* in_sizes, int n_in,
                              void* d_out, int out_size, void* d_ws, size_t ws_size,
                              hipStream_t stream)
{
  const float* x        = (const float*)d_in[0];
  const float* y        = (const float*)d_in[1];
  const float* mask     = (const float*)d_in[2];
  const float* mask2    = (const float*)d_in[3];
  const float* qkv_w    = (const float*)d_in[4];
  const float* qkv_b    = (const float*)d_in[5];
  const float* sa_out_w = (const float*)d_in[6];
  const float* sa_out_b = (const float*)d_in[7];
  const float* q_w      = (const float*)d_in[8];
  const float* q_b      = (const float*)d_in[9];
  const float* kv_w     = (const float*)d_in[10];
  const float* kv_b     = (const float*)d_in[11];
  const float* ca_out_w = (const float*)d_in[12];
  const float* ca_out_b = (const float*)d_in[13];
  const float* l1_w     = (const float*)d_in[14];
  const float* l1_b     = (const float*)d_in[15];
  const float* l2_w     = (const float*)d_in[16];
  const float* l2_b     = (const float*)d_in[17];
  const float* g1 = (const float*)d_in[18];
  const float* b1 = (const float*)d_in[19];
  const float* g2 = (const float*)d_in[20];
  const float* b2 = (const float*)d_in[21];
  const float* g3 = (const float*)d_in[22];
  const float* b3 = (const float*)d_in[23];

  const int B  = in_sizes[1] / (SDEC * DMODEL);   // 256
  const int M  = B * SDEC;                        // 16384 decoder tokens
  const int ME = B * SENC;                        // 131072 encoder tokens

  char* ws = (char*)d_ws;
  size_t off = 0;
  auto alloc = [&](size_t bytes) -> char* {
    char* p = ws + off;
    off += (bytes + 255) & ~(size_t)255;
    return p;
  };
  // persistent regions
  unsigned short* qkv_wt = (unsigned short*)alloc((size_t)1536 * 512 * 2);
  unsigned short* sa_wt  = (unsigned short*)alloc((size_t)512 * 512 * 2);
  unsigned short* q_wt   = (unsigned short*)alloc((size_t)512 * 512 * 2);
  unsigned short* kv_wt  = (unsigned short*)alloc((size_t)1024 * 512 * 2);
  unsigned short* ca_wt  = (unsigned short*)alloc((size_t)512 * 512 * 2);
  unsigned short* l1_wt  = (unsigned short*)alloc((size_t)2048 * 512 * 2);
  unsigned short* l2_wt  = (unsigned short*)alloc((size_t)512 * 2048 * 2);
  unsigned short* kvb    = (unsigned short*)alloc((size_t)ME * 1024 * 2);  // 256 MiB
  char*           xreg   = alloc((size_t)ME * 512 * 2);                    // 128 MiB region
  // xreg aliases (xb dead after kv gemm; qkvb dead after self-attn):
  unsigned short* xb     = (unsigned short*)xreg;
  unsigned short* qkvb   = (unsigned short*)xreg;                          // 48 MiB
  unsigned short* qb     = (unsigned short*)xreg;                          // 16 MiB (after self-attn)
  unsigned short* y2b    = (unsigned short*)(xreg + (size_t)16777216);     // @16 MiB
  unsigned short* valsb  = (unsigned short*)(xreg + (size_t)50331648);     // @48 MiB
  unsigned short* proj   = (unsigned short*)(xreg + (size_t)67108864);     // @64 MiB (bf16)
  unsigned short* y1b    = (unsigned short*)(xreg + (size_t)100663296);    // @96 MiB
  unsigned short* yb     = (unsigned short*)(xreg + (size_t)117440512);    // @112 MiB
  unsigned short* hb     = kvb;  // FFN hidden aliases kv (kv dead after cross-attn)
  (void)ws_size; (void)n_in; (void)out_size;

  // --- weight transposes (f32 [K,N] -> bf16 [N,K]) ---
  dim3 tb(32, 8);
  transpose_cvt<<<dim3(1536 / 32, 512 / 32), tb, 0, stream>>>(qkv_w, qkv_wt, 512, 1536);
  transpose_cvt<<<dim3(512 / 32, 512 / 32), tb, 0, stream>>>(sa_out_w, sa_wt, 512, 512);
  transpose_cvt<<<dim3(512 / 32, 512 / 32), tb, 0, stream>>>(q_w, q_wt, 512, 512);
  transpose_cvt<<<dim3(1024 / 32, 512 / 32), tb, 0, stream>>>(kv_w, kv_wt, 512, 1024);
  transpose_cvt<<<dim3(512 / 32, 512 / 32), tb, 0, stream>>>(ca_out_w, ca_wt, 512, 512);
  transpose_cvt<<<dim3(2048 / 32, 512 / 32), tb, 0, stream>>>(l1_w, l1_wt, 512, 2048);
  transpose_cvt<<<dim3(512 / 32, 2048 / 32), tb, 0, stream>>>(l2_w, l2_wt, 2048, 512);

  const float scale = 0.125f;  // 1/sqrt(64)

  // --- kv projection (x -> bf16, then BK=64 GEMM; xb dead afterwards) ---
  cvt_f32_bf16<<<4096, 256, 0, stream>>>(x, xb, (size_t)ME * 512 / 8);
  gemm_bk64_kernel<0><<<dim3(1024 / 128, ME / 128), 256, 0, stream>>>(xb, kv_wt, kv_b, kvb, ME, 1024, 512);

  // --- self attention ---
  cvt_f32_bf16<<<4096, 256, 0, stream>>>(y, yb, (size_t)M * 512 / 8);
  gemm_bk64_kernel<0><<<dim3(1536 / 128, M / 128), 256, 0, stream>>>(yb, qkv_wt, qkv_b, qkvb, M, 1536, 512);
  // qkv row layout per token: head h -> [h*192 .. ): q(64) | k(64) | v(64)
  attn_mfma<<<dim3(8, B), 256, 0, stream>>>(qkvb, 1536, 192, qkvb, 1536, 192, 64, SDEC, SDEC, mask, valsb, scale);
  gemm_kernel<0><<<dim3(512 / 128, M / 128), 256, 0, stream>>>(valsb, sa_wt, sa_out_b, proj, M, 512, 512);
  ln_kernel<<<M / 4, 256, 0, stream>>>(proj, y, nullptr, g1, b1, y1b, nullptr);

  // --- cross attention ---
  gemm_kernel<0><<<dim3(512 / 128, M / 128), 256, 0, stream>>>(y1b, q_wt, q_b, qb, M, 512, 512);
  // kv row layout per token: head h -> [h*128 .. ): k(64) | v(64)
  attn_mfma<<<dim3(8, B), 256, 0, stream>>>(qb, 512, 64, kvb, 1024, 128, 0, SENC, SENC, mask2, valsb, scale);
  gemm_kernel<0><<<dim3(512 / 128, M / 128), 256, 0, stream>>>(valsb, ca_wt, ca_out_b, proj, M, 512, 512);
  ln_kernel<<<M / 4, 256, 0, stream>>>(proj, nullptr, y1b, g2, b2, y2b, nullptr);

  // --- FFN ---
  gemm_bk64_kernel<1><<<dim3(2048 / 128, M / 128), 256, 0, stream>>>(y2b, l1_wt, l1_b, hb, M, 2048, 512);
  gemm_bk64_kernel<0><<<dim3(512 / 128, M / 128), 256, 0, stream>>>(hb, l2_wt, l2_b, proj, M, 512, 2048);
  ln_kernel<<<M / 4, 256, 0, stream>>>(proj, nullptr, y2b, g3, b3, nullptr, (float*)d_out);
}

// Round 12
// 611.338 us; speedup vs baseline: 1.0683x; 1.0683x over previous
//
#include <hip/hip_runtime.h>
#include <hip/hip_bf16.h>
#include <stdint.h>

// Transformer decoder layer: B=256, Sd=64, Se=512, D=512, H=8, HD=64, FF=2048.
// f32 in/out; internal compute bf16 MFMA (tolerance is 2% of ref absmax).

#define SDEC 64
#define SENC 512
#define DMODEL 512
#define FFDIM 2048

typedef __bf16 bf16x8 __attribute__((ext_vector_type(8)));
typedef float  f32x4  __attribute__((ext_vector_type(4)));

static __device__ __forceinline__ float bf2f(unsigned short u) {
  union { unsigned int i; float f; } w; w.i = ((unsigned int)u) << 16; return w.f;
}
static __device__ __forceinline__ unsigned short f2bf(float f) {
  union { float f; unsigned int i; } w; w.f = f;
  unsigned int u = w.i;
  return (unsigned short)((u + 0x7fffu + ((u >> 16) & 1u)) >> 16);  // RTNE
}

// Async global->LDS, 16B per lane. LDS dest = wave-uniform base + lane*16.
static __device__ __forceinline__ void gl_lds16(const unsigned short* g, unsigned short* l) {
  __builtin_amdgcn_global_load_lds(
      (const __attribute__((address_space(1))) unsigned int*)g,
      (__attribute__((address_space(3))) unsigned int*)l,
      16, 0, 0);
}

// ---------------------------------------------------------------------------
// f32 -> bf16 elementwise convert (RTNE), 8 elems/thread/iter, grid-stride.
// ---------------------------------------------------------------------------
__global__ __launch_bounds__(256)
void cvt_f32_bf16(const float* __restrict__ in, unsigned short* __restrict__ out, size_t n8)
{
  size_t i = (size_t)blockIdx.x * blockDim.x + threadIdx.x;
  const size_t stride = (size_t)gridDim.x * blockDim.x;
  for (; i < n8; i += stride) {
    const float* p = in + i * 8;
    float4 a = *(const float4*)p, b = *(const float4*)(p + 4);
    union { unsigned short s[8]; uint4 v; } u;
    u.s[0] = f2bf(a.x); u.s[1] = f2bf(a.y); u.s[2] = f2bf(a.z); u.s[3] = f2bf(a.w);
    u.s[4] = f2bf(b.x); u.s[5] = f2bf(b.y); u.s[6] = f2bf(b.z); u.s[7] = f2bf(b.w);
    *(uint4*)(out + i * 8) = u.v;
  }
}

// ---------------------------------------------------------------------------
// 128x128 GEMM (R8-proven best: 2-buf dbuf, gl_lds w=16, counted vmcnt(4),
// raw s_barrier, zero-conflict both-sides swizzle, swizzled LDS epilogue).
// Used for ALL seven GEMMs (structural plateau established R4-R10).
// ---------------------------------------------------------------------------
#define GEMM_COMPUTE(asrc, bsrc)                                                     \
  {                                                                                  \
    const unsigned short* as_ = (asrc);                                              \
    const unsigned short* bs_ = (bsrc);                                              \
    bf16x8 af[4], bfr[4];                                                            \
    _Pragma("unroll")                                                                \
    for (int mi = 0; mi < 4; ++mi)                                                   \
      af[mi] = *(const bf16x8*)&as_[(wm * 64 + mi * 16 + fr) * 32 + fsw];            \
    _Pragma("unroll")                                                                \
    for (int ni = 0; ni < 4; ++ni)                                                   \
      bfr[ni] = *(const bf16x8*)&bs_[(wn * 64 + ni * 16 + fr) * 32 + fsw];           \
    _Pragma("unroll")                                                                \
    for (int mi = 0; mi < 4; ++mi)                                                   \
      _Pragma("unroll")                                                              \
      for (int ni = 0; ni < 4; ++ni)                                                 \
        acc[mi][ni] = __builtin_amdgcn_mfma_f32_16x16x32_bf16(af[mi], bfr[ni],       \
                                                              acc[mi][ni], 0, 0, 0); \
  }

template<int RELU>
__global__ __launch_bounds__(256, 2)
void gemm_kernel(const unsigned short* __restrict__ A, const unsigned short* __restrict__ Bt,
                 const float* __restrict__ bias, unsigned short* __restrict__ C,
                 int M, int N, int K)
{
  __shared__ unsigned short sh[2 * 8192];   // 2 bufs x (A 8KB | B 8KB) = 32 KB
  const int tid = threadIdx.x;

  const int gx   = gridDim.x;
  const int nwg  = gx * gridDim.y;
  const int orig = blockIdx.y * gx + blockIdx.x;
  const int wg   = (orig & 7) * (nwg >> 3) + (orig >> 3);
  const int row0 = (wg / gx) * 128;
  const int col0 = (wg % gx) * 128;

  const int w = tid >> 6, lane = tid & 63;
  const int wm = w >> 1, wn = w & 1;
  const int gr = lane >> 2;
  const int gc = ((lane & 3) ^ ((lane >> 3) & 3)) * 8;   // pre-swizzled global chunk

  auto STAGE = [&](int k0, int buf) {
    unsigned short* as = sh + buf * 8192;
    unsigned short* bs = as + 4096;
    #pragma unroll
    for (int i = 0; i < 2; ++i) {
      const int rbase = w * 32 + i * 16;   // wave-uniform, % 16 == 0
      gl_lds16(A  + (size_t)(row0 + rbase + gr) * K + (k0 + gc), as + rbase * 32);
      gl_lds16(Bt + (size_t)(col0 + rbase + gr) * K + (k0 + gc), bs + rbase * 32);
    }
  };

  f32x4 acc[4][4];
  #pragma unroll
  for (int i = 0; i < 4; ++i)
    #pragma unroll
    for (int j = 0; j < 4; ++j)
      acc[i][j] = (f32x4){0.f, 0.f, 0.f, 0.f};

  const int fr  = lane & 15;
  const int fg  = lane >> 4;
  const int fsw = (fg ^ ((fr >> 1) & 3)) * 8;   // swizzled fragment chunk offset

  STAGE(0, 0);
  int cur = 0;
  for (int k0 = 0; k0 + 32 < K; k0 += 32) {
    STAGE(k0 + 32, cur ^ 1);                          // prefetch next tile
    asm volatile("s_waitcnt vmcnt(4)" ::: "memory");  // own tile's loads done
    __builtin_amdgcn_s_barrier();                     // all waves: tile visible
    asm volatile("" ::: "memory");
    GEMM_COMPUTE(sh + cur * 8192, sh + cur * 8192 + 4096);
    asm volatile("" ::: "memory");
    __builtin_amdgcn_s_barrier();                     // reads of buf[cur] done
    cur ^= 1;
  }
  asm volatile("s_waitcnt vmcnt(0)" ::: "memory");
  __builtin_amdgcn_s_barrier();
  asm volatile("" ::: "memory");
  GEMM_COMPUTE(sh + cur * 8192, sh + cur * 8192 + 4096);
  asm volatile("" ::: "memory");
  __builtin_amdgcn_s_barrier();   // LDS free for epilogue reuse

  // Epilogue: LDS-staged, swizzled (phys col = c ^ (fq<<4); 2-way = free).
  {
    const int fq = lane >> 4;
    #pragma unroll
    for (int ni = 0; ni < 4; ++ni) {
      const int c = wn * 64 + ni * 16 + fr;
      const float bv = bias ? bias[col0 + c] : 0.f;
      #pragma unroll
      for (int mi = 0; mi < 4; ++mi) {
        #pragma unroll
        for (int t = 0; t < 4; ++t) {
          const int r = wm * 64 + mi * 16 + fq * 4 + t;
          float v = acc[mi][ni][t] + bv;
          if (RELU) v = fmaxf(v, 0.f);
          sh[r * 128 + (c ^ (fq << 4))] = f2bf(v);
        }
      }
    }
    __syncthreads();
    const int rr = tid >> 4;
    const int cc = (tid & 15) * 8;
    #pragma unroll
    for (int p = 0; p < 8; ++p) {
      const int r = p * 16 + rr;
      *(uint4*)(C + (size_t)(row0 + r) * N + col0 + cc) =
          *(const uint4*)&sh[r * 128 + (cc ^ (w << 4))];
    }
  }
}

// ---------------------------------------------------------------------------
// MFMA flash attention (R8-proven layouts + two safe schedule fixes):
//  - T14 prefetch: tile t+1's K/V global loads issued right after tile t's
//    LDS writes; they stay in flight across the barrier (raw s_barrier with
//    lgkmcnt(0) only -- __syncthreads would vmcnt(0)-drain them).
//  - post-softmax barrier removed (Ps slabs are wave-private; within-wave
//    LDS RAW is compiler-lgkmcnt-ordered).
// One block (4 waves) per (b,h); 64 q-rows, HD=64; padded 72-short rows;
// scalar V transpose (proven correct R2-R10). XCD-chunked block swizzle.
// ---------------------------------------------------------------------------
__global__ __launch_bounds__(256, 2)
void attn_mfma(const unsigned short* __restrict__ qbuf, int qstride, int qmul,
               const unsigned short* __restrict__ kvbuf, int kvstride, int kmul, int kadd,
               int tokmul, int Skv, const float* __restrict__ mask,
               unsigned short* __restrict__ vals, float scale)
{
  __shared__ unsigned short Qs[64 * 72];   // pad 72 shorts: 144B rows, 16B-aligned
  __shared__ unsigned short Ks[64 * 72];
  __shared__ unsigned short Vt[64 * 72];   // [d][j] (transposed V tile)
  __shared__ unsigned short Ps[64 * 72];   // [row][j], wave-private 16-row slabs

  const int nwg  = gridDim.x * gridDim.y;          // 8 * B, % 8 == 0
  const int orig = blockIdx.y * gridDim.x + blockIdx.x;
  const int wg   = (orig & 7) * (nwg >> 3) + (orig >> 3);
  const int h = wg & 7, b = wg >> 3;

  const int tid = threadIdx.x;
  const int w = tid >> 6, lane = tid & 63;
  const int srow = tid >> 2;          // 0..63 staging row (token)
  const int sc0 = (tid & 3) * 16;     // 0,16,32,48 staging col (d)

  // stage Q once
  {
    const unsigned short* qg = qbuf + (size_t)(b * 64 + srow) * qstride + h * qmul + sc0;
    *(uint4*)&Qs[srow * 72 + sc0]     = *(const uint4*)qg;
    *(uint4*)&Qs[srow * 72 + sc0 + 8] = *(const uint4*)(qg + 8);
  }

  const int fr = lane & 15;    // A/B frag row index
  const int fg = lane >> 4;    // frag k-group
  const int orow = fg * 4;     // C/D row base within 16-slice

  float mstate[4], lstate[4];
  f32x4 oacc[4];
  #pragma unroll
  for (int t = 0; t < 4; ++t) { mstate[t] = -1e30f; lstate[t] = 0.f; }
  #pragma unroll
  for (int ni = 0; ni < 4; ++ni) oacc[ni] = (f32x4){0.f, 0.f, 0.f, 0.f};

  // K/V register prefetch (16 VGPRs): loads issued early, consumed next tile
  uint4 kr0, kr1, vr0, vr1;
  auto LOADKV = [&](int j0) {
    const unsigned short* kg = kvbuf + (size_t)(b * tokmul + j0 + srow) * kvstride
                               + h * kmul + kadd + sc0;
    kr0 = *(const uint4*)kg;
    kr1 = *(const uint4*)(kg + 8);
    vr0 = *(const uint4*)(kg + 64);   // V sits 64 shorts after K
    vr1 = *(const uint4*)(kg + 72);
  };
  LOADKV(0);

  const int NT = Skv >> 6;
  for (int t = 0; t < NT; ++t) {
    // (A) all waves' LDS reads of the previous tile are complete
    asm volatile("s_waitcnt lgkmcnt(0)" ::: "memory");
    __builtin_amdgcn_s_barrier();
    asm volatile("" ::: "memory");

    // write tile t registers into LDS (K rows; V transposed, scalar)
    *(uint4*)&Ks[srow * 72 + sc0]     = kr0;
    *(uint4*)&Ks[srow * 72 + sc0 + 8] = kr1;
    {
      const unsigned short* vsp = (const unsigned short*)&vr0;
      #pragma unroll
      for (int jj = 0; jj < 8; ++jj) Vt[(sc0 + jj) * 72 + srow] = vsp[jj];
      vsp = (const unsigned short*)&vr1;
      #pragma unroll
      for (int jj = 0; jj < 8; ++jj) Vt[(sc0 + 8 + jj) * 72 + srow] = vsp[jj];
    }
    if (t + 1 < NT) LOADKV((t + 1) * 64);   // prefetch next tile (in flight past barrier)

    // (B) tile t staged & visible; lgkmcnt only -- keep prefetch loads flying
    asm volatile("s_waitcnt lgkmcnt(0)" ::: "memory");
    __builtin_amdgcn_s_barrier();
    asm volatile("" ::: "memory");

    // --- S = Q @ K^T (wave's 16-row slice x 64 key cols) ---
    f32x4 s4[4];
    #pragma unroll
    for (int ni = 0; ni < 4; ++ni) s4[ni] = (f32x4){0.f, 0.f, 0.f, 0.f};
    #pragma unroll
    for (int ks = 0; ks < 2; ++ks) {
      bf16x8 aq = *(const bf16x8*)&Qs[(w * 16 + fr) * 72 + ks * 32 + fg * 8];
      #pragma unroll
      for (int ni = 0; ni < 4; ++ni) {
        bf16x8 bk = *(const bf16x8*)&Ks[(ni * 16 + fr) * 72 + ks * 32 + fg * 8];
        s4[ni] = __builtin_amdgcn_mfma_f32_16x16x32_bf16(aq, bk, s4[ni], 0, 0, 0);
      }
    }

    // --- online softmax (lane owns rows orow..orow+3 of wave slice) ---
    #pragma unroll
    for (int t4 = 0; t4 < 4; ++t4) {
      const int grow = w * 16 + orow + t4;
      const float* mrow = mask + ((size_t)b * 64 + grow) * Skv + t * 64;
      float sv[4];
      float tmax = -1e30f;
      #pragma unroll
      for (int ni = 0; ni < 4; ++ni) {
        sv[ni] = s4[ni][t4] * scale + mrow[ni * 16 + fr];
        tmax = fmaxf(tmax, sv[ni]);
      }
      #pragma unroll
      for (int off = 1; off < 16; off <<= 1) tmax = fmaxf(tmax, __shfl_xor(tmax, off));
      const float mn = fmaxf(mstate[t4], tmax);
      const float fscl = __expf(mstate[t4] - mn);
      mstate[t4] = mn;
      float psum = 0.f;
      #pragma unroll
      for (int ni = 0; ni < 4; ++ni) {
        float p = __expf(sv[ni] - mn);
        psum += p;
        Ps[grow * 72 + ni * 16 + fr] = f2bf(p);
      }
      #pragma unroll
      for (int off = 1; off < 16; off <<= 1) psum += __shfl_xor(psum, off);
      lstate[t4] = lstate[t4] * fscl + psum;
      #pragma unroll
      for (int ni = 0; ni < 4; ++ni) oacc[ni][t4] *= fscl;
    }
    // Ps slabs wave-private (rows w*16..w*16+15 written AND read by wave w)
    // -> no barrier; compiler orders the Ps RAW via lgkmcnt.

    // --- O += P @ V   (A = Ps rows, B = Vt rows) ---
    #pragma unroll
    for (int ks = 0; ks < 2; ++ks) {
      bf16x8 pa = *(const bf16x8*)&Ps[(w * 16 + fr) * 72 + ks * 32 + fg * 8];
      #pragma unroll
      for (int ni = 0; ni < 4; ++ni) {
        bf16x8 vb = *(const bf16x8*)&Vt[(ni * 16 + fr) * 72 + ks * 32 + fg * 8];
        oacc[ni] = __builtin_amdgcn_mfma_f32_16x16x32_bf16(pa, vb, oacc[ni], 0, 0, 0);
      }
    }
  }

  // epilogue: normalize, write head block
  #pragma unroll
  for (int t4 = 0; t4 < 4; ++t4) {
    const int grow = w * 16 + orow + t4;
    const float inv = 1.f / lstate[t4];
    unsigned short* og = vals + (size_t)(b * 64 + grow) * DMODEL + h * 64;
    #pragma unroll
    for (int ni = 0; ni < 4; ++ni)
      og[ni * 16 + fr] = f2bf(oacc[ni][t4] * inv);
  }
}

// ---------------------------------------------------------------------------
// LayerNorm over D=512 with fused residual add. One wave per row, 8 elems/lane.
// proj input is bf16. resid32 XOR resid16 non-null; out16 and/or out32.
// ---------------------------------------------------------------------------
__global__ __launch_bounds__(256)
void ln_kernel(const unsigned short* __restrict__ proj16, const float* __restrict__ resid32,
               const unsigned short* __restrict__ resid16,
               const float* __restrict__ gamma, const float* __restrict__ beta,
               unsigned short* __restrict__ out16, float* __restrict__ out32)
{
  const int w = threadIdx.x >> 6, lane = threadIdx.x & 63;
  const size_t r = (size_t)blockIdx.x * 4 + w;
  const int d0 = lane * 8;

  float x[8];
  {
    uint4 u = *(const uint4*)(proj16 + r * DMODEL + d0);
    const unsigned short* s = (const unsigned short*)&u;
    #pragma unroll
    for (int j = 0; j < 8; ++j) x[j] = bf2f(s[j]);
  }
  if (resid32) {
    const float* p = resid32 + r * DMODEL + d0;
    float4 a = *(const float4*)p, b = *(const float4*)(p + 4);
    x[0] += a.x; x[1] += a.y; x[2] += a.z; x[3] += a.w;
    x[4] += b.x; x[5] += b.y; x[6] += b.z; x[7] += b.w;
  } else {
    uint4 u = *(const uint4*)(resid16 + r * DMODEL + d0);
    const unsigned short* s = (const unsigned short*)&u;
    #pragma unroll
    for (int j = 0; j < 8; ++j) x[j] += bf2f(s[j]);
  }

  float sum = 0.f;
  #pragma unroll
  for (int j = 0; j < 8; ++j) sum += x[j];
  #pragma unroll
  for (int off = 32; off > 0; off >>= 1) sum += __shfl_xor(sum, off);
  const float mean = sum * (1.f / DMODEL);

  float vs = 0.f;
  #pragma unroll
  for (int j = 0; j < 8; ++j) { float t = x[j] - mean; vs += t * t; }
  #pragma unroll
  for (int off = 32; off > 0; off >>= 1) vs += __shfl_xor(vs, off);
  const float rstd = rsqrtf(vs * (1.f / DMODEL) + 1e-5f);

  float4 g0 = *(const float4*)(gamma + d0), g1 = *(const float4*)(gamma + d0 + 4);
  float4 b0 = *(const float4*)(beta + d0),  b1 = *(const float4*)(beta + d0 + 4);
  const float g[8]  = {g0.x, g0.y, g0.z, g0.w, g1.x, g1.y, g1.z, g1.w};
  const float bb[8] = {b0.x, b0.y, b0.z, b0.w, b1.x, b1.y, b1.z, b1.w};
  float y[8];
  #pragma unroll
  for (int j = 0; j < 8; ++j) y[j] = g[j] * (x[j] - mean) * rstd + bb[j];

  if (out16) {
    union { unsigned short s[8]; uint4 v; } p;
    #pragma unroll
    for (int j = 0; j < 8; ++j) p.s[j] = f2bf(y[j]);
    *(uint4*)(out16 + r * DMODEL + d0) = p.v;
  }
  if (out32) {
    float* o = out32 + r * DMODEL + d0;
    *(float4*)o       = (float4){y[0], y[1], y[2], y[3]};
    *(float4*)(o + 4) = (float4){y[4], y[5], y[6], y[7]};
  }
}

// ---------------------------------------------------------------------------
// Transpose + f32->bf16 convert: W[K,N] f32 -> Wt[N,K] bf16. 32x32 LDS tiles.
// ---------------------------------------------------------------------------
__global__ __launch_bounds__(256)
void transpose_cvt(const float* __restrict__ W, unsigned short* __restrict__ Wt,
                   int K, int N)
{
  __shared__ float tile[32][33];
  const int tx = threadIdx.x, ty = threadIdx.y;
  const int n = blockIdx.x * 32 + tx;
  #pragma unroll
  for (int rr = 0; rr < 4; ++rr) {
    const int k = blockIdx.y * 32 + ty + rr * 8;
    tile[ty + rr * 8][tx] = W[(size_t)k * N + n];
  }
  __syncthreads();
  const int k2 = blockIdx.y * 32 + tx;
  #pragma unroll
  for (int rr = 0; rr < 4; ++rr) {
    const int n2 = blockIdx.x * 32 + ty + rr * 8;
    Wt[(size_t)n2 * K + k2] = f2bf(tile[tx][ty + rr * 8]);
  }
}

// ---------------------------------------------------------------------------
extern "C" void kernel_launch(void* const* d_in, const int* in_sizes, int n_in,
                              void* d_out, int out_size, void* d_ws, size_t ws_size,
                              hipStream_t stream)
{
  const float* x        = (const float*)d_in[0];
  const float* y        = (const float*)d_in[1];
  const float* mask     = (const float*)d_in[2];
  const float* mask2    = (const float*)d_in[3];
  const float* qkv_w    = (const float*)d_in[4];
  const float* qkv_b    = (const float*)d_in[5];
  const float* sa_out_w = (const float*)d_in[6];
  const float* sa_out_b = (const float*)d_in[7];
  const float* q_w      = (const float*)d_in[8];
  const float* q_b      = (const float*)d_in[9];
  const float* kv_w     = (const float*)d_in[10];
  const float* kv_b     = (const float*)d_in[11];
  const float* ca_out_w = (const float*)d_in[12];
  const float* ca_out_b = (const float*)d_in[13];
  const float* l1_w     = (const float*)d_in[14];
  const float* l1_b     = (const float*)d_in[15];
  const float* l2_w     = (const float*)d_in[16];
  const float* l2_b     = (const float*)d_in[17];
  const float* g1 = (const float*)d_in[18];
  const float* b1 = (const float*)d_in[19];
  const float* g2 = (const float*)d_in[20];
  const float* b2 = (const float*)d_in[21];
  const float* g3 = (const float*)d_in[22];
  const float* b3 = (const float*)d_in[23];

  const int B  = in_sizes[1] / (SDEC * DMODEL);   // 256
  const int M  = B * SDEC;                        // 16384 decoder tokens
  const int ME = B * SENC;                        // 131072 encoder tokens

  char* ws = (char*)d_ws;
  size_t off = 0;
  auto alloc = [&](size_t bytes) -> char* {
    char* p = ws + off;
    off += (bytes + 255) & ~(size_t)255;
    return p;
  };
  // persistent regions
  unsigned short* qkv_wt = (unsigned short*)alloc((size_t)1536 * 512 * 2);
  unsigned short* sa_wt  = (unsigned short*)alloc((size_t)512 * 512 * 2);
  unsigned short* q_wt   = (unsigned short*)alloc((size_t)512 * 512 * 2);
  unsigned short* kv_wt  = (unsigned short*)alloc((size_t)1024 * 512 * 2);
  unsigned short* ca_wt  = (unsigned short*)alloc((size_t)512 * 512 * 2);
  unsigned short* l1_wt  = (unsigned short*)alloc((size_t)2048 * 512 * 2);
  unsigned short* l2_wt  = (unsigned short*)alloc((size_t)512 * 2048 * 2);
  unsigned short* kvb    = (unsigned short*)alloc((size_t)ME * 1024 * 2);  // 256 MiB
  char*           xreg   = alloc((size_t)ME * 512 * 2);                    // 128 MiB region
  // xreg aliases (xb dead after kv gemm; qkvb dead after self-attn):
  unsigned short* xb     = (unsigned short*)xreg;
  unsigned short* qkvb   = (unsigned short*)xreg;                          // 48 MiB
  unsigned short* qb     = (unsigned short*)xreg;                          // 16 MiB (after self-attn)
  unsigned short* y2b    = (unsigned short*)(xreg + (size_t)16777216);     // @16 MiB
  unsigned short* valsb  = (unsigned short*)(xreg + (size_t)50331648);     // @48 MiB
  unsigned short* proj   = (unsigned short*)(xreg + (size_t)67108864);     // @64 MiB (bf16)
  unsigned short* y1b    = (unsigned short*)(xreg + (size_t)100663296);    // @96 MiB
  unsigned short* yb     = (unsigned short*)(xreg + (size_t)117440512);    // @112 MiB
  unsigned short* hb     = kvb;  // FFN hidden aliases kv (kv dead after cross-attn)
  (void)ws_size; (void)n_in; (void)out_size;

  // --- weight transposes (f32 [K,N] -> bf16 [N,K]) ---
  dim3 tb(32, 8);
  transpose_cvt<<<dim3(1536 / 32, 512 / 32), tb, 0, stream>>>(qkv_w, qkv_wt, 512, 1536);
  transpose_cvt<<<dim3(512 / 32, 512 / 32), tb, 0, stream>>>(sa_out_w, sa_wt, 512, 512);
  transpose_cvt<<<dim3(512 / 32, 512 / 32), tb, 0, stream>>>(q_w, q_wt, 512, 512);
  transpose_cvt<<<dim3(1024 / 32, 512 / 32), tb, 0, stream>>>(kv_w, kv_wt, 512, 1024);
  transpose_cvt<<<dim3(512 / 32, 512 / 32), tb, 0, stream>>>(ca_out_w, ca_wt, 512, 512);
  transpose_cvt<<<dim3(2048 / 32, 512 / 32), tb, 0, stream>>>(l1_w, l1_wt, 512, 2048);
  transpose_cvt<<<dim3(512 / 32, 2048 / 32), tb, 0, stream>>>(l2_w, l2_wt, 2048, 512);

  const float scale = 0.125f;  // 1/sqrt(64)

  // --- kv projection (x -> bf16, then GEMM; xb dead afterwards) ---
  cvt_f32_bf16<<<4096, 256, 0, stream>>>(x, xb, (size_t)ME * 512 / 8);
  gemm_kernel<0><<<dim3(1024 / 128, ME / 128), 256, 0, stream>>>(xb, kv_wt, kv_b, kvb, ME, 1024, 512);

  // --- self attention ---
  cvt_f32_bf16<<<4096, 256, 0, stream>>>(y, yb, (size_t)M * 512 / 8);
  gemm_kernel<0><<<dim3(1536 / 128, M / 128), 256, 0, stream>>>(yb, qkv_wt, qkv_b, qkvb, M, 1536, 512);
  // qkv row layout per token: head h -> [h*192 .. ): q(64) | k(64) | v(64)
  attn_mfma<<<dim3(8, B), 256, 0, stream>>>(qkvb, 1536, 192, qkvb, 1536, 192, 64, SDEC, SDEC, mask, valsb, scale);
  gemm_kernel<0><<<dim3(512 / 128, M / 128), 256, 0, stream>>>(valsb, sa_wt, sa_out_b, proj, M, 512, 512);
  ln_kernel<<<M / 4, 256, 0, stream>>>(proj, y, nullptr, g1, b1, y1b, nullptr);

  // --- cross attention ---
  gemm_kernel<0><<<dim3(512 / 128, M / 128), 256, 0, stream>>>(y1b, q_wt, q_b, qb, M, 512, 512);
  // kv row layout per token: head h -> [h*128 .. ): k(64) | v(64)
  attn_mfma<<<dim3(8, B), 256, 0, stream>>>(qb, 512, 64, kvb, 1024, 128, 0, SENC, SENC, mask2, valsb, scale);
  gemm_kernel<0><<<dim3(512 / 128, M / 128), 256, 0, stream>>>(valsb, ca_wt, ca_out_b, proj, M, 512, 512);
  ln_kernel<<<M / 4, 256, 0, stream>>>(proj, nullptr, y1b, g2, b2, y2b, nullptr);

  // --- FFN ---
  gemm_kernel<1><<<dim3(2048 / 128, M / 128), 256, 0, stream>>>(y2b, l1_wt, l1_b, hb, M, 2048, 512);
  gemm_kernel<0><<<dim3(512 / 128, M / 128), 256, 0, stream>>>(hb, l2_wt, l2_b, proj, M, 512, 2048);
  ln_kernel<<<M / 4, 256, 0, stream>>>(proj, nullptr, y2b, g3, b3, nullptr, (float*)d_out);
}

// Round 13
// 597.430 us; speedup vs baseline: 1.0932x; 1.0233x over previous
//
#include <hip/hip_runtime.h>
#include <hip/hip_bf16.h>
#include <stdint.h>

// Transformer decoder layer: B=256, Sd=64, Se=512, D=512, H=8, HD=64, FF=2048.
// f32 in/out; internal compute bf16 MFMA (tolerance is 2% of ref absmax).

#define SDEC 64
#define SENC 512
#define DMODEL 512
#define FFDIM 2048

typedef __bf16 bf16x8 __attribute__((ext_vector_type(8)));
typedef float  f32x4  __attribute__((ext_vector_type(4)));

static __device__ __forceinline__ float bf2f(unsigned short u) {
  union { unsigned int i; float f; } w; w.i = ((unsigned int)u) << 16; return w.f;
}
static __device__ __forceinline__ unsigned short f2bf(float f) {
  union { float f; unsigned int i; } w; w.f = f;
  unsigned int u = w.i;
  return (unsigned short)((u + 0x7fffu + ((u >> 16) & 1u)) >> 16);  // RTNE
}

// Async global->LDS, 16B per lane. LDS dest = wave-uniform base + lane*16.
static __device__ __forceinline__ void gl_lds16(const void* g, void* l) {
  __builtin_amdgcn_global_load_lds(
      (const __attribute__((address_space(1))) unsigned int*)g,
      (__attribute__((address_space(3))) unsigned int*)l,
      16, 0, 0);
}

// pack 8 f32 -> bf16x8 via v_cvt_pk_bf16_f32 (RNE)
static __device__ __forceinline__ bf16x8 pk_bf16(const f32x4& a, const f32x4& b) {
  union { unsigned int u[4]; bf16x8 v; } r;
  asm("v_cvt_pk_bf16_f32 %0, %1, %2" : "=v"(r.u[0]) : "v"(a[0]), "v"(a[1]));
  asm("v_cvt_pk_bf16_f32 %0, %1, %2" : "=v"(r.u[1]) : "v"(a[2]), "v"(a[3]));
  asm("v_cvt_pk_bf16_f32 %0, %1, %2" : "=v"(r.u[2]) : "v"(b[0]), "v"(b[1]));
  asm("v_cvt_pk_bf16_f32 %0, %1, %2" : "=v"(r.u[3]) : "v"(b[2]), "v"(b[3]));
  return r.v;
}

// ---------------------------------------------------------------------------
// 128x128 GEMM, R8 skeleton (2-buf dbuf, gl_lds w=16, counted vmcnt, raw
// s_barrier, both-sides XOR swizzle -> conflicts ~0, swizzled LDS epilogue).
// A_F32=1: A staged DIRECTLY from f32 global via gl_lds (async, 4 calls/wave),
//   LDS A tile = [128 rows][32 f32] (128B rows, 8 chunks); phys chunk =
//   logical ^ (row&7) (2 lanes/bank-quad = free); fragments read as 2x b128
//   f32 and packed to bf16 with v_cvt_pk (VALU has ~70% headroom).
//   Replaces the separate cvt kernel + xb round-trip entirely.
// ---------------------------------------------------------------------------
template<int A_F32, int RELU>
__global__ __launch_bounds__(256, 2)
void gemm_kernel(const void* __restrict__ Aptr, const unsigned short* __restrict__ Bt,
                 const float* __restrict__ bias, unsigned short* __restrict__ C,
                 int M, int N, int K)
{
  // A_F32: bufs = 2 x (A 16KB | B 8KB) = 48 KB ; else 2 x (A 8KB | B 8KB) = 32 KB
  __shared__ unsigned short sh[A_F32 ? 24576 : 16384];
  const int ABUF = A_F32 ? 8192 : 4096;           // A buf size in shorts
  const int BUFS = ABUF + 4096;                   // total per-buf shorts
  const int tid = threadIdx.x;

  const int gx   = gridDim.x;
  const int nwg  = gx * gridDim.y;
  const int orig = blockIdx.y * gx + blockIdx.x;
  const int wg   = (orig & 7) * (nwg >> 3) + (orig >> 3);
  const int row0 = (wg / gx) * 128;
  const int col0 = (wg % gx) * 128;

  const int w = tid >> 6, lane = tid & 63;
  const int wm = w >> 1, wn = w & 1;
  // bf16 staging coords (B always; A when !A_F32): 16 rows/call, 4 chunks of 8 shorts
  const int gr = lane >> 2;
  const int gc = ((lane & 3) ^ ((lane >> 3) & 3)) * 8;
  // f32 A staging coords: 8 rows/call, 8 chunks of 4 floats
  const int fgr = lane >> 3;
  const int fgc = ((lane & 7) ^ (lane >> 3)) * 4;     // floats

  auto STAGE = [&](int k0, int buf) {
    unsigned short* as = sh + buf * BUFS;
    unsigned short* bs = as + ABUF;
    if (A_F32) {
      const float* A = (const float*)Aptr;
      #pragma unroll
      for (int i = 0; i < 4; ++i) {
        const int rbase = w * 32 + i * 8;   // wave-uniform, % 8 == 0
        gl_lds16(A + (size_t)(row0 + rbase + fgr) * K + (k0 + fgc), as + rbase * 64);
      }
    } else {
      const unsigned short* A = (const unsigned short*)Aptr;
      #pragma unroll
      for (int i = 0; i < 2; ++i) {
        const int rbase = w * 32 + i * 16;   // wave-uniform, % 16 == 0
        gl_lds16(A + (size_t)(row0 + rbase + gr) * K + (k0 + gc), as + rbase * 32);
      }
    }
    #pragma unroll
    for (int i = 0; i < 2; ++i) {
      const int rbase = w * 32 + i * 16;
      gl_lds16(Bt + (size_t)(col0 + rbase + gr) * K + (k0 + gc), bs + rbase * 32);
    }
  };

  f32x4 acc[4][4];
  #pragma unroll
  for (int i = 0; i < 4; ++i)
    #pragma unroll
    for (int j = 0; j < 4; ++j)
      acc[i][j] = (f32x4){0.f, 0.f, 0.f, 0.f};

  const int fr  = lane & 15;
  const int fg  = lane >> 4;
  const int fsw = (fg ^ ((fr >> 1) & 3)) * 8;   // bf16 swizzled fragment chunk

  auto COMPUTE = [&](int buf) {
    const unsigned short* as = sh + buf * BUFS;
    const unsigned short* bs = as + ABUF;
    bf16x8 af[4], bfr[4];
    if (A_F32) {
      const float* asf = (const float*)as;
      #pragma unroll
      for (int mi = 0; mi < 4; ++mi) {
        const int row = wm * 64 + mi * 16 + fr;
        const int c0 = ((fg * 2) ^ (fr & 7)) * 4;
        const int c1 = ((fg * 2 + 1) ^ (fr & 7)) * 4;
        f32x4 a0 = *(const f32x4*)&asf[row * 32 + c0];
        f32x4 a1 = *(const f32x4*)&asf[row * 32 + c1];
        af[mi] = pk_bf16(a0, a1);
      }
    } else {
      #pragma unroll
      for (int mi = 0; mi < 4; ++mi)
        af[mi] = *(const bf16x8*)&as[(wm * 64 + mi * 16 + fr) * 32 + fsw];
    }
    #pragma unroll
    for (int ni = 0; ni < 4; ++ni)
      bfr[ni] = *(const bf16x8*)&bs[(wn * 64 + ni * 16 + fr) * 32 + fsw];
    #pragma unroll
    for (int mi = 0; mi < 4; ++mi)
      #pragma unroll
      for (int ni = 0; ni < 4; ++ni)
        acc[mi][ni] = __builtin_amdgcn_mfma_f32_16x16x32_bf16(af[mi], bfr[ni], acc[mi][ni], 0, 0, 0);
  };

  STAGE(0, 0);
  int cur = 0;
  for (int k0 = 0; k0 + 32 < K; k0 += 32) {
    STAGE(k0 + 32, cur ^ 1);                          // prefetch next tile
    if (A_F32) asm volatile("s_waitcnt vmcnt(6)" ::: "memory");  // own 6 landed
    else       asm volatile("s_waitcnt vmcnt(4)" ::: "memory");  // own 4 landed
    __builtin_amdgcn_s_barrier();                     // all waves: tile visible
    asm volatile("" ::: "memory");
    COMPUTE(cur);
    asm volatile("" ::: "memory");
    __builtin_amdgcn_s_barrier();                     // reads of buf[cur] done
    cur ^= 1;
  }
  asm volatile("s_waitcnt vmcnt(0)" ::: "memory");
  __builtin_amdgcn_s_barrier();
  asm volatile("" ::: "memory");
  COMPUTE(cur);
  asm volatile("" ::: "memory");
  __builtin_amdgcn_s_barrier();   // LDS free for epilogue reuse

  // Epilogue: LDS-staged, swizzled (phys col = c ^ (fq<<4); 2-way = free).
  {
    const int fq = lane >> 4;
    #pragma unroll
    for (int ni = 0; ni < 4; ++ni) {
      const int c = wn * 64 + ni * 16 + fr;
      const float bv = bias ? bias[col0 + c] : 0.f;
      #pragma unroll
      for (int mi = 0; mi < 4; ++mi) {
        #pragma unroll
        for (int t = 0; t < 4; ++t) {
          const int r = wm * 64 + mi * 16 + fq * 4 + t;
          float v = acc[mi][ni][t] + bv;
          if (RELU) v = fmaxf(v, 0.f);
          sh[r * 128 + (c ^ (fq << 4))] = f2bf(v);
        }
      }
    }
    __syncthreads();
    const int rr = tid >> 4;
    const int cc = (tid & 15) * 8;
    #pragma unroll
    for (int p = 0; p < 8; ++p) {
      const int r = p * 16 + rr;
      *(uint4*)(C + (size_t)(row0 + r) * N + col0 + cc) =
          *(const uint4*)&sh[r * 128 + (cc ^ (w << 4))];
    }
  }
}

// ---------------------------------------------------------------------------
// MFMA flash attention (R12: T14 reg-prefetch of K/V, lgkmcnt-only barriers,
// no post-softmax barrier; R8-proven layouts; scalar V transpose).
// One block (4 waves) per (b,h). XCD-chunked block swizzle.
// ---------------------------------------------------------------------------
__global__ __launch_bounds__(256, 2)
void attn_mfma(const unsigned short* __restrict__ qbuf, int qstride, int qmul,
               const unsigned short* __restrict__ kvbuf, int kvstride, int kmul, int kadd,
               int tokmul, int Skv, const float* __restrict__ mask,
               unsigned short* __restrict__ vals, float scale)
{
  __shared__ unsigned short Qs[64 * 72];
  __shared__ unsigned short Ks[64 * 72];
  __shared__ unsigned short Vt[64 * 72];   // [d][j] (transposed V tile)
  __shared__ unsigned short Ps[64 * 72];   // wave-private 16-row slabs

  const int nwg  = gridDim.x * gridDim.y;          // 8 * B, % 8 == 0
  const int orig = blockIdx.y * gridDim.x + blockIdx.x;
  const int wg   = (orig & 7) * (nwg >> 3) + (orig >> 3);
  const int h = wg & 7, b = wg >> 3;

  const int tid = threadIdx.x;
  const int w = tid >> 6, lane = tid & 63;
  const int srow = tid >> 2;
  const int sc0 = (tid & 3) * 16;

  {
    const unsigned short* qg = qbuf + (size_t)(b * 64 + srow) * qstride + h * qmul + sc0;
    *(uint4*)&Qs[srow * 72 + sc0]     = *(const uint4*)qg;
    *(uint4*)&Qs[srow * 72 + sc0 + 8] = *(const uint4*)(qg + 8);
  }

  const int fr = lane & 15;
  const int fg = lane >> 4;
  const int orow = fg * 4;

  float mstate[4], lstate[4];
  f32x4 oacc[4];
  #pragma unroll
  for (int t = 0; t < 4; ++t) { mstate[t] = -1e30f; lstate[t] = 0.f; }
  #pragma unroll
  for (int ni = 0; ni < 4; ++ni) oacc[ni] = (f32x4){0.f, 0.f, 0.f, 0.f};

  uint4 kr0, kr1, vr0, vr1;
  auto LOADKV = [&](int j0) {
    const unsigned short* kg = kvbuf + (size_t)(b * tokmul + j0 + srow) * kvstride
                               + h * kmul + kadd + sc0;
    kr0 = *(const uint4*)kg;
    kr1 = *(const uint4*)(kg + 8);
    vr0 = *(const uint4*)(kg + 64);
    vr1 = *(const uint4*)(kg + 72);
  };
  LOADKV(0);

  const int NT = Skv >> 6;
  for (int t = 0; t < NT; ++t) {
    asm volatile("s_waitcnt lgkmcnt(0)" ::: "memory");
    __builtin_amdgcn_s_barrier();
    asm volatile("" ::: "memory");

    *(uint4*)&Ks[srow * 72 + sc0]     = kr0;
    *(uint4*)&Ks[srow * 72 + sc0 + 8] = kr1;
    {
      const unsigned short* vsp = (const unsigned short*)&vr0;
      #pragma unroll
      for (int jj = 0; jj < 8; ++jj) Vt[(sc0 + jj) * 72 + srow] = vsp[jj];
      vsp = (const unsigned short*)&vr1;
      #pragma unroll
      for (int jj = 0; jj < 8; ++jj) Vt[(sc0 + 8 + jj) * 72 + srow] = vsp[jj];
    }
    if (t + 1 < NT) LOADKV((t + 1) * 64);

    asm volatile("s_waitcnt lgkmcnt(0)" ::: "memory");
    __builtin_amdgcn_s_barrier();
    asm volatile("" ::: "memory");

    f32x4 s4[4];
    #pragma unroll
    for (int ni = 0; ni < 4; ++ni) s4[ni] = (f32x4){0.f, 0.f, 0.f, 0.f};
    #pragma unroll
    for (int ks = 0; ks < 2; ++ks) {
      bf16x8 aq = *(const bf16x8*)&Qs[(w * 16 + fr) * 72 + ks * 32 + fg * 8];
      #pragma unroll
      for (int ni = 0; ni < 4; ++ni) {
        bf16x8 bk = *(const bf16x8*)&Ks[(ni * 16 + fr) * 72 + ks * 32 + fg * 8];
        s4[ni] = __builtin_amdgcn_mfma_f32_16x16x32_bf16(aq, bk, s4[ni], 0, 0, 0);
      }
    }

    #pragma unroll
    for (int t4 = 0; t4 < 4; ++t4) {
      const int grow = w * 16 + orow + t4;
      const float* mrow = mask + ((size_t)b * 64 + grow) * Skv + t * 64;
      float sv[4];
      float tmax = -1e30f;
      #pragma unroll
      for (int ni = 0; ni < 4; ++ni) {
        sv[ni] = s4[ni][t4] * scale + mrow[ni * 16 + fr];
        tmax = fmaxf(tmax, sv[ni]);
      }
      #pragma unroll
      for (int off = 1; off < 16; off <<= 1) tmax = fmaxf(tmax, __shfl_xor(tmax, off));
      const float mn = fmaxf(mstate[t4], tmax);
      const float fscl = __expf(mstate[t4] - mn);
      mstate[t4] = mn;
      float psum = 0.f;
      #pragma unroll
      for (int ni = 0; ni < 4; ++ni) {
        float p = __expf(sv[ni] - mn);
        psum += p;
        Ps[grow * 72 + ni * 16 + fr] = f2bf(p);
      }
      #pragma unroll
      for (int off = 1; off < 16; off <<= 1) psum += __shfl_xor(psum, off);
      lstate[t4] = lstate[t4] * fscl + psum;
      #pragma unroll
      for (int ni = 0; ni < 4; ++ni) oacc[ni][t4] *= fscl;
    }

    #pragma unroll
    for (int ks = 0; ks < 2; ++ks) {
      bf16x8 pa = *(const bf16x8*)&Ps[(w * 16 + fr) * 72 + ks * 32 + fg * 8];
      #pragma unroll
      for (int ni = 0; ni < 4; ++ni) {
        bf16x8 vb = *(const bf16x8*)&Vt[(ni * 16 + fr) * 72 + ks * 32 + fg * 8];
        oacc[ni] = __builtin_amdgcn_mfma_f32_16x16x32_bf16(pa, vb, oacc[ni], 0, 0, 0);
      }
    }
  }

  #pragma unroll
  for (int t4 = 0; t4 < 4; ++t4) {
    const int grow = w * 16 + orow + t4;
    const float inv = 1.f / lstate[t4];
    unsigned short* og = vals + (size_t)(b * 64 + grow) * DMODEL + h * 64;
    #pragma unroll
    for (int ni = 0; ni < 4; ++ni)
      og[ni * 16 + fr] = f2bf(oacc[ni][t4] * inv);
  }
}

// ---------------------------------------------------------------------------
// LayerNorm over D=512 with fused residual add. One wave per row, 8 elems/lane.
// ---------------------------------------------------------------------------
__global__ __launch_bounds__(256)
void ln_kernel(const unsigned short* __restrict__ proj16, const float* __restrict__ resid32,
               const unsigned short* __restrict__ resid16,
               const float* __restrict__ gamma, const float* __restrict__ beta,
               unsigned short* __restrict__ out16, float* __restrict__ out32)
{
  const int w = threadIdx.x >> 6, lane = threadIdx.x & 63;
  const size_t r = (size_t)blockIdx.x * 4 + w;
  const int d0 = lane * 8;

  float x[8];
  {
    uint4 u = *(const uint4*)(proj16 + r * DMODEL + d0);
    const unsigned short* s = (const unsigned short*)&u;
    #pragma unroll
    for (int j = 0; j < 8; ++j) x[j] = bf2f(s[j]);
  }
  if (resid32) {
    const float* p = resid32 + r * DMODEL + d0;
    float4 a = *(const float4*)p, b = *(const float4*)(p + 4);
    x[0] += a.x; x[1] += a.y; x[2] += a.z; x[3] += a.w;
    x[4] += b.x; x[5] += b.y; x[6] += b.z; x[7] += b.w;
  } else {
    uint4 u = *(const uint4*)(resid16 + r * DMODEL + d0);
    const unsigned short* s = (const unsigned short*)&u;
    #pragma unroll
    for (int j = 0; j < 8; ++j) x[j] += bf2f(s[j]);
  }

  float sum = 0.f;
  #pragma unroll
  for (int j = 0; j < 8; ++j) sum += x[j];
  #pragma unroll
  for (int off = 32; off > 0; off >>= 1) sum += __shfl_xor(sum, off);
  const float mean = sum * (1.f / DMODEL);

  float vs = 0.f;
  #pragma unroll
  for (int j = 0; j < 8; ++j) { float t = x[j] - mean; vs += t * t; }
  #pragma unroll
  for (int off = 32; off > 0; off >>= 1) vs += __shfl_xor(vs, off);
  const float rstd = rsqrtf(vs * (1.f / DMODEL) + 1e-5f);

  float4 g0 = *(const float4*)(gamma + d0), g1 = *(const float4*)(gamma + d0 + 4);
  float4 b0 = *(const float4*)(beta + d0),  b1 = *(const float4*)(beta + d0 + 4);
  const float g[8]  = {g0.x, g0.y, g0.z, g0.w, g1.x, g1.y, g1.z, g1.w};
  const float bb[8] = {b0.x, b0.y, b0.z, b0.w, b1.x, b1.y, b1.z, b1.w};
  float y[8];
  #pragma unroll
  for (int j = 0; j < 8; ++j) y[j] = g[j] * (x[j] - mean) * rstd + bb[j];

  if (out16) {
    union { unsigned short s[8]; uint4 v; } p;
    #pragma unroll
    for (int j = 0; j < 8; ++j) p.s[j] = f2bf(y[j]);
    *(uint4*)(out16 + r * DMODEL + d0) = p.v;
  }
  if (out32) {
    float* o = out32 + r * DMODEL + d0;
    *(float4*)o       = (float4){y[0], y[1], y[2], y[3]};
    *(float4*)(o + 4) = (float4){y[4], y[5], y[6], y[7]};
  }
}

// ---------------------------------------------------------------------------
// Transpose + f32->bf16 convert: W[K,N] f32 -> Wt[N,K] bf16. 32x32 LDS tiles.
// ---------------------------------------------------------------------------
__global__ __launch_bounds__(256)
void transpose_cvt(const float* __restrict__ W, unsigned short* __restrict__ Wt,
                   int K, int N)
{
  __shared__ float tile[32][33];
  const int tx = threadIdx.x, ty = threadIdx.y;
  const int n = blockIdx.x * 32 + tx;
  #pragma unroll
  for (int rr = 0; rr < 4; ++rr) {
    const int k = blockIdx.y * 32 + ty + rr * 8;
    tile[ty + rr * 8][tx] = W[(size_t)k * N + n];
  }
  __syncthreads();
  const int k2 = blockIdx.y * 32 + tx;
  #pragma unroll
  for (int rr = 0; rr < 4; ++rr) {
    const int n2 = blockIdx.x * 32 + ty + rr * 8;
    Wt[(size_t)n2 * K + k2] = f2bf(tile[tx][ty + rr * 8]);
  }
}

// ---------------------------------------------------------------------------
extern "C" void kernel_launch(void* const* d_in, const int* in_sizes, int n_in,
                              void* d_out, int out_size, void* d_ws, size_t ws_size,
                              hipStream_t stream)
{
  const float* x        = (const float*)d_in[0];
  const float* y        = (const float*)d_in[1];
  const float* mask     = (const float*)d_in[2];
  const float* mask2    = (const float*)d_in[3];
  const float* qkv_w    = (const float*)d_in[4];
  const float* qkv_b    = (const float*)d_in[5];
  const float* sa_out_w = (const float*)d_in[6];
  const float* sa_out_b = (const float*)d_in[7];
  const float* q_w      = (const float*)d_in[8];
  const float* q_b      = (const float*)d_in[9];
  const float* kv_w     = (const float*)d_in[10];
  const float* kv_b     = (const float*)d_in[11];
  const float* ca_out_w = (const float*)d_in[12];
  const float* ca_out_b = (const float*)d_in[13];
  const float* l1_w     = (const float*)d_in[14];
  const float* l1_b     = (const float*)d_in[15];
  const float* l2_w     = (const float*)d_in[16];
  const float* l2_b     = (const float*)d_in[17];
  const float* g1 = (const float*)d_in[18];
  const float* b1 = (const float*)d_in[19];
  const float* g2 = (const float*)d_in[20];
  const float* b2 = (const float*)d_in[21];
  const float* g3 = (const float*)d_in[22];
  const float* b3 = (const float*)d_in[23];

  const int B  = in_sizes[1] / (SDEC * DMODEL);   // 256
  const int M  = B * SDEC;                        // 16384 decoder tokens
  const int ME = B * SENC;                        // 131072 encoder tokens

  char* ws = (char*)d_ws;
  size_t off = 0;
  auto alloc = [&](size_t bytes) -> char* {
    char* p = ws + off;
    off += (bytes + 255) & ~(size_t)255;
    return p;
  };
  // persistent regions
  unsigned short* qkv_wt = (unsigned short*)alloc((size_t)1536 * 512 * 2);
  unsigned short* sa_wt  = (unsigned short*)alloc((size_t)512 * 512 * 2);
  unsigned short* q_wt   = (unsigned short*)alloc((size_t)512 * 512 * 2);
  unsigned short* kv_wt  = (unsigned short*)alloc((size_t)1024 * 512 * 2);
  unsigned short* ca_wt  = (unsigned short*)alloc((size_t)512 * 512 * 2);
  unsigned short* l1_wt  = (unsigned short*)alloc((size_t)2048 * 512 * 2);
  unsigned short* l2_wt  = (unsigned short*)alloc((size_t)512 * 2048 * 2);
  unsigned short* kvb    = (unsigned short*)alloc((size_t)ME * 1024 * 2);  // 256 MiB
  char*           xreg   = alloc((size_t)ME * 512 * 2);                    // 128 MiB region
  // xreg aliases (qkvb dead after self-attn):
  unsigned short* qkvb   = (unsigned short*)xreg;                          // 48 MiB
  unsigned short* qb     = (unsigned short*)xreg;                          // 16 MiB (after self-attn)
  unsigned short* y2b    = (unsigned short*)(xreg + (size_t)16777216);     // @16 MiB
  unsigned short* valsb  = (unsigned short*)(xreg + (size_t)50331648);     // @48 MiB
  unsigned short* proj   = (unsigned short*)(xreg + (size_t)67108864);     // @64 MiB (bf16)
  unsigned short* y1b    = (unsigned short*)(xreg + (size_t)100663296);    // @96 MiB
  unsigned short* hb     = kvb;  // FFN hidden aliases kv (kv dead after cross-attn)
  (void)ws_size; (void)n_in; (void)out_size;

  // --- weight transposes (f32 [K,N] -> bf16 [N,K]) ---
  dim3 tb(32, 8);
  transpose_cvt<<<dim3(1536 / 32, 512 / 32), tb, 0, stream>>>(qkv_w, qkv_wt, 512, 1536);
  transpose_cvt<<<dim3(512 / 32, 512 / 32), tb, 0, stream>>>(sa_out_w, sa_wt, 512, 512);
  transpose_cvt<<<dim3(512 / 32, 512 / 32), tb, 0, stream>>>(q_w, q_wt, 512, 512);
  transpose_cvt<<<dim3(1024 / 32, 512 / 32), tb, 0, stream>>>(kv_w, kv_wt, 512, 1024);
  transpose_cvt<<<dim3(512 / 32, 512 / 32), tb, 0, stream>>>(ca_out_w, ca_wt, 512, 512);
  transpose_cvt<<<dim3(2048 / 32, 512 / 32), tb, 0, stream>>>(l1_w, l1_wt, 512, 2048);
  transpose_cvt<<<dim3(512 / 32, 2048 / 32), tb, 0, stream>>>(l2_w, l2_wt, 2048, 512);

  const float scale = 0.125f;  // 1/sqrt(64)

  // --- kv projection: reads x f32 directly (cvt fused into async A-staging) ---
  gemm_kernel<1, 0><<<dim3(1024 / 128, ME / 128), 256, 0, stream>>>(x, kv_wt, kv_b, kvb, ME, 1024, 512);

  // --- self attention (qkv reads y f32 directly) ---
  gemm_kernel<1, 0><<<dim3(1536 / 128, M / 128), 256, 0, stream>>>(y, qkv_wt, qkv_b, qkvb, M, 1536, 512);
  // qkv row layout per token: head h -> [h*192 .. ): q(64) | k(64) | v(64)
  attn_mfma<<<dim3(8, B), 256, 0, stream>>>(qkvb, 1536, 192, qkvb, 1536, 192, 64, SDEC, SDEC, mask, valsb, scale);
  gemm_kernel<0, 0><<<dim3(512 / 128, M / 128), 256, 0, stream>>>(valsb, sa_wt, sa_out_b, proj, M, 512, 512);
  ln_kernel<<<M / 4, 256, 0, stream>>>(proj, y, nullptr, g1, b1, y1b, nullptr);

  // --- cross attention ---
  gemm_kernel<0, 0><<<dim3(512 / 128, M / 128), 256, 0, stream>>>(y1b, q_wt, q_b, qb, M, 512, 512);
  // kv row layout per token: head h -> [h*128 .. ): k(64) | v(64)
  attn_mfma<<<dim3(8, B), 256, 0, stream>>>(qb, 512, 64, kvb, 1024, 128, 0, SENC, SENC, mask2, valsb, scale);
  gemm_kernel<0, 0><<<dim3(512 / 128, M / 128), 256, 0, stream>>>(valsb, ca_wt, ca_out_b, proj, M, 512, 512);
  ln_kernel<<<M / 4, 256, 0, stream>>>(proj, nullptr, y1b, g2, b2, y2b, nullptr);

  // --- FFN ---
  gemm_kernel<0, 1><<<dim3(2048 / 128, M / 128), 256, 0, stream>>>(y2b, l1_wt, l1_b, hb, M, 2048, 512);
  gemm_kernel<0, 0><<<dim3(512 / 128, M / 128), 256, 0, stream>>>(hb, l2_wt, l2_b, proj, M, 512, 2048);
  ln_kernel<<<M / 4, 256, 0, stream>>>(proj, nullptr, y2b, g3, b3, nullptr, (float*)d_out);
}

// Round 14
// 593.541 us; speedup vs baseline: 1.1004x; 1.0066x over previous
//
#include <hip/hip_runtime.h>
#include <hip/hip_bf16.h>
#include <stdint.h>

// Transformer decoder layer: B=256, Sd=64, Se=512, D=512, H=8, HD=64, FF=2048.
// f32 in/out; internal compute bf16 MFMA (tolerance is 2% of ref absmax).

#define SDEC 64
#define SENC 512
#define DMODEL 512
#define FFDIM 2048

typedef __bf16 bf16x8 __attribute__((ext_vector_type(8)));
typedef float  f32x4  __attribute__((ext_vector_type(4)));

static __device__ __forceinline__ float bf2f(unsigned short u) {
  union { unsigned int i; float f; } w; w.i = ((unsigned int)u) << 16; return w.f;
}
static __device__ __forceinline__ unsigned short f2bf(float f) {
  union { float f; unsigned int i; } w; w.f = f;
  unsigned int u = w.i;
  return (unsigned short)((u + 0x7fffu + ((u >> 16) & 1u)) >> 16);  // RTNE
}

// Async global->LDS, 16B per lane. LDS dest = wave-uniform base + lane*16.
static __device__ __forceinline__ void gl_lds16(const void* g, void* l) {
  __builtin_amdgcn_global_load_lds(
      (const __attribute__((address_space(1))) unsigned int*)g,
      (__attribute__((address_space(3))) unsigned int*)l,
      16, 0, 0);
}

// pack 8 f32 -> bf16x8 via v_cvt_pk_bf16_f32 (RNE)
static __device__ __forceinline__ bf16x8 pk_bf16(const f32x4& a, const f32x4& b) {
  union { unsigned int u[4]; bf16x8 v; } r;
  asm("v_cvt_pk_bf16_f32 %0, %1, %2" : "=v"(r.u[0]) : "v"(a[0]), "v"(a[1]));
  asm("v_cvt_pk_bf16_f32 %0, %1, %2" : "=v"(r.u[1]) : "v"(a[2]), "v"(a[3]));
  asm("v_cvt_pk_bf16_f32 %0, %1, %2" : "=v"(r.u[2]) : "v"(b[0]), "v"(b[1]));
  asm("v_cvt_pk_bf16_f32 %0, %1, %2" : "=v"(r.u[3]) : "v"(b[2]), "v"(b[3]));
  return r.v;
}

// ---------------------------------------------------------------------------
// 128x128 GEMM, R8 skeleton (2-buf dbuf, gl_lds w=16, counted vmcnt, raw
// s_barrier, XOR swizzles, swizzled LDS epilogue).
// A_F32=1: A staged f32 via gl_lds, packed to bf16 at fragment read (R13).
// RES: 0 = none; 1 = add f32 residual; 2 = add bf16 residual -- fused into
// the coalesced copy-out (reads are latency-hidden; LN becomes single-input).
// ---------------------------------------------------------------------------
template<int A_F32, int RELU, int RES>
__global__ __launch_bounds__(256, 2)
void gemm_kernel(const void* __restrict__ Aptr, const unsigned short* __restrict__ Bt,
                 const float* __restrict__ bias, const void* __restrict__ resid,
                 unsigned short* __restrict__ C, int M, int N, int K)
{
  __shared__ unsigned short sh[A_F32 ? 24576 : 16384];
  const int ABUF = A_F32 ? 8192 : 4096;           // A buf size in shorts
  const int BUFS = ABUF + 4096;                   // total per-buf shorts
  const int tid = threadIdx.x;

  const int gx   = gridDim.x;
  const int nwg  = gx * gridDim.y;
  const int orig = blockIdx.y * gx + blockIdx.x;
  const int wg   = (orig & 7) * (nwg >> 3) + (orig >> 3);
  const int row0 = (wg / gx) * 128;
  const int col0 = (wg % gx) * 128;

  const int w = tid >> 6, lane = tid & 63;
  const int wm = w >> 1, wn = w & 1;
  const int gr = lane >> 2;
  const int gc = ((lane & 3) ^ ((lane >> 3) & 3)) * 8;
  const int fgr = lane >> 3;
  const int fgc = ((lane & 7) ^ (lane >> 3)) * 4;     // floats

  auto STAGE = [&](int k0, int buf) {
    unsigned short* as = sh + buf * BUFS;
    unsigned short* bs = as + ABUF;
    if (A_F32) {
      const float* A = (const float*)Aptr;
      #pragma unroll
      for (int i = 0; i < 4; ++i) {
        const int rbase = w * 32 + i * 8;
        gl_lds16(A + (size_t)(row0 + rbase + fgr) * K + (k0 + fgc), as + rbase * 64);
      }
    } else {
      const unsigned short* A = (const unsigned short*)Aptr;
      #pragma unroll
      for (int i = 0; i < 2; ++i) {
        const int rbase = w * 32 + i * 16;
        gl_lds16(A + (size_t)(row0 + rbase + gr) * K + (k0 + gc), as + rbase * 32);
      }
    }
    #pragma unroll
    for (int i = 0; i < 2; ++i) {
      const int rbase = w * 32 + i * 16;
      gl_lds16(Bt + (size_t)(col0 + rbase + gr) * K + (k0 + gc), bs + rbase * 32);
    }
  };

  f32x4 acc[4][4];
  #pragma unroll
  for (int i = 0; i < 4; ++i)
    #pragma unroll
    for (int j = 0; j < 4; ++j)
      acc[i][j] = (f32x4){0.f, 0.f, 0.f, 0.f};

  const int fr  = lane & 15;
  const int fg  = lane >> 4;
  const int fsw = (fg ^ ((fr >> 1) & 3)) * 8;

  auto COMPUTE = [&](int buf) {
    const unsigned short* as = sh + buf * BUFS;
    const unsigned short* bs = as + ABUF;
    bf16x8 af[4], bfr[4];
    if (A_F32) {
      const float* asf = (const float*)as;
      #pragma unroll
      for (int mi = 0; mi < 4; ++mi) {
        const int row = wm * 64 + mi * 16 + fr;
        const int c0 = ((fg * 2) ^ (fr & 7)) * 4;
        const int c1 = ((fg * 2 + 1) ^ (fr & 7)) * 4;
        f32x4 a0 = *(const f32x4*)&asf[row * 32 + c0];
        f32x4 a1 = *(const f32x4*)&asf[row * 32 + c1];
        af[mi] = pk_bf16(a0, a1);
      }
    } else {
      #pragma unroll
      for (int mi = 0; mi < 4; ++mi)
        af[mi] = *(const bf16x8*)&as[(wm * 64 + mi * 16 + fr) * 32 + fsw];
    }
    #pragma unroll
    for (int ni = 0; ni < 4; ++ni)
      bfr[ni] = *(const bf16x8*)&bs[(wn * 64 + ni * 16 + fr) * 32 + fsw];
    #pragma unroll
    for (int mi = 0; mi < 4; ++mi)
      #pragma unroll
      for (int ni = 0; ni < 4; ++ni)
        acc[mi][ni] = __builtin_amdgcn_mfma_f32_16x16x32_bf16(af[mi], bfr[ni], acc[mi][ni], 0, 0, 0);
  };

  STAGE(0, 0);
  int cur = 0;
  for (int k0 = 0; k0 + 32 < K; k0 += 32) {
    STAGE(k0 + 32, cur ^ 1);
    if (A_F32) asm volatile("s_waitcnt vmcnt(6)" ::: "memory");
    else       asm volatile("s_waitcnt vmcnt(4)" ::: "memory");
    __builtin_amdgcn_s_barrier();
    asm volatile("" ::: "memory");
    COMPUTE(cur);
    asm volatile("" ::: "memory");
    __builtin_amdgcn_s_barrier();
    cur ^= 1;
  }
  asm volatile("s_waitcnt vmcnt(0)" ::: "memory");
  __builtin_amdgcn_s_barrier();
  asm volatile("" ::: "memory");
  COMPUTE(cur);
  asm volatile("" ::: "memory");
  __builtin_amdgcn_s_barrier();   // LDS free for epilogue reuse

  // Epilogue: acc -> swizzled LDS -> coalesced copy-out (+ fused residual add)
  {
    const int fq = lane >> 4;
    #pragma unroll
    for (int ni = 0; ni < 4; ++ni) {
      const int c = wn * 64 + ni * 16 + fr;
      const float bv = bias ? bias[col0 + c] : 0.f;
      #pragma unroll
      for (int t = 0; t < 4; ++t) {
        #pragma unroll
        for (int mi = 0; mi < 4; ++mi) {
          const int r = wm * 64 + mi * 16 + fq * 4 + t;
          float v = acc[mi][ni][t] + bv;
          if (RELU) v = fmaxf(v, 0.f);
          sh[r * 128 + (c ^ (fq << 4))] = f2bf(v);
        }
      }
    }
    __syncthreads();
    const int rr = tid >> 4;
    const int cc = (tid & 15) * 8;
    #pragma unroll
    for (int p = 0; p < 8; ++p) {
      const int r = p * 16 + rr;
      union { unsigned short s[8]; uint4 v; } o;
      o.v = *(const uint4*)&sh[r * 128 + (cc ^ (w << 4))];
      if (RES == 1) {
        const float* rp = (const float*)resid + (size_t)(row0 + r) * N + col0 + cc;
        float4 r0 = *(const float4*)rp, r1 = *(const float4*)(rp + 4);
        o.s[0] = f2bf(bf2f(o.s[0]) + r0.x); o.s[1] = f2bf(bf2f(o.s[1]) + r0.y);
        o.s[2] = f2bf(bf2f(o.s[2]) + r0.z); o.s[3] = f2bf(bf2f(o.s[3]) + r0.w);
        o.s[4] = f2bf(bf2f(o.s[4]) + r1.x); o.s[5] = f2bf(bf2f(o.s[5]) + r1.y);
        o.s[6] = f2bf(bf2f(o.s[6]) + r1.z); o.s[7] = f2bf(bf2f(o.s[7]) + r1.w);
      } else if (RES == 2) {
        const unsigned short* rp = (const unsigned short*)resid + (size_t)(row0 + r) * N + col0 + cc;
        uint4 ru = *(const uint4*)rp;
        const unsigned short* rs = (const unsigned short*)&ru;
        #pragma unroll
        for (int j = 0; j < 8; ++j) o.s[j] = f2bf(bf2f(o.s[j]) + bf2f(rs[j]));
      }
      *(uint4*)(C + (size_t)(row0 + r) * N + col0 + cc) = o.v;
    }
  }
}

// ---------------------------------------------------------------------------
// MFMA flash attention (R12/R13 proven: T14 reg-prefetch of K/V, lgkmcnt-only
// barriers, no post-softmax barrier, scalar V transpose, XCD swizzle).
// ---------------------------------------------------------------------------
__global__ __launch_bounds__(256, 2)
void attn_mfma(const unsigned short* __restrict__ qbuf, int qstride, int qmul,
               const unsigned short* __restrict__ kvbuf, int kvstride, int kmul, int kadd,
               int tokmul, int Skv, const float* __restrict__ mask,
               unsigned short* __restrict__ vals, float scale)
{
  __shared__ unsigned short Qs[64 * 72];
  __shared__ unsigned short Ks[64 * 72];
  __shared__ unsigned short Vt[64 * 72];
  __shared__ unsigned short Ps[64 * 72];

  const int nwg  = gridDim.x * gridDim.y;
  const int orig = blockIdx.y * gridDim.x + blockIdx.x;
  const int wg   = (orig & 7) * (nwg >> 3) + (orig >> 3);
  const int h = wg & 7, b = wg >> 3;

  const int tid = threadIdx.x;
  const int w = tid >> 6, lane = tid & 63;
  const int srow = tid >> 2;
  const int sc0 = (tid & 3) * 16;

  {
    const unsigned short* qg = qbuf + (size_t)(b * 64 + srow) * qstride + h * qmul + sc0;
    *(uint4*)&Qs[srow * 72 + sc0]     = *(const uint4*)qg;
    *(uint4*)&Qs[srow * 72 + sc0 + 8] = *(const uint4*)(qg + 8);
  }

  const int fr = lane & 15;
  const int fg = lane >> 4;
  const int orow = fg * 4;

  float mstate[4], lstate[4];
  f32x4 oacc[4];
  #pragma unroll
  for (int t = 0; t < 4; ++t) { mstate[t] = -1e30f; lstate[t] = 0.f; }
  #pragma unroll
  for (int ni = 0; ni < 4; ++ni) oacc[ni] = (f32x4){0.f, 0.f, 0.f, 0.f};

  uint4 kr0, kr1, vr0, vr1;
  auto LOADKV = [&](int j0) {
    const unsigned short* kg = kvbuf + (size_t)(b * tokmul + j0 + srow) * kvstride
                               + h * kmul + kadd + sc0;
    kr0 = *(const uint4*)kg;
    kr1 = *(const uint4*)(kg + 8);
    vr0 = *(const uint4*)(kg + 64);
    vr1 = *(const uint4*)(kg + 72);
  };
  LOADKV(0);

  const int NT = Skv >> 6;
  for (int t = 0; t < NT; ++t) {
    asm volatile("s_waitcnt lgkmcnt(0)" ::: "memory");
    __builtin_amdgcn_s_barrier();
    asm volatile("" ::: "memory");

    *(uint4*)&Ks[srow * 72 + sc0]     = kr0;
    *(uint4*)&Ks[srow * 72 + sc0 + 8] = kr1;
    {
      const unsigned short* vsp = (const unsigned short*)&vr0;
      #pragma unroll
      for (int jj = 0; jj < 8; ++jj) Vt[(sc0 + jj) * 72 + srow] = vsp[jj];
      vsp = (const unsigned short*)&vr1;
      #pragma unroll
      for (int jj = 0; jj < 8; ++jj) Vt[(sc0 + 8 + jj) * 72 + srow] = vsp[jj];
    }
    if (t + 1 < NT) LOADKV((t + 1) * 64);

    asm volatile("s_waitcnt lgkmcnt(0)" ::: "memory");
    __builtin_amdgcn_s_barrier();
    asm volatile("" ::: "memory");

    f32x4 s4[4];
    #pragma unroll
    for (int ni = 0; ni < 4; ++ni) s4[ni] = (f32x4){0.f, 0.f, 0.f, 0.f};
    #pragma unroll
    for (int ks = 0; ks < 2; ++ks) {
      bf16x8 aq = *(const bf16x8*)&Qs[(w * 16 + fr) * 72 + ks * 32 + fg * 8];
      #pragma unroll
      for (int ni = 0; ni < 4; ++ni) {
        bf16x8 bk = *(const bf16x8*)&Ks[(ni * 16 + fr) * 72 + ks * 32 + fg * 8];
        s4[ni] = __builtin_amdgcn_mfma_f32_16x16x32_bf16(aq, bk, s4[ni], 0, 0, 0);
      }
    }

    #pragma unroll
    for (int t4 = 0; t4 < 4; ++t4) {
      const int grow = w * 16 + orow + t4;
      const float* mrow = mask + ((size_t)b * 64 + grow) * Skv + t * 64;
      float sv[4];
      float tmax = -1e30f;
      #pragma unroll
      for (int ni = 0; ni < 4; ++ni) {
        sv[ni] = s4[ni][t4] * scale + mrow[ni * 16 + fr];
        tmax = fmaxf(tmax, sv[ni]);
      }
      #pragma unroll
      for (int off = 1; off < 16; off <<= 1) tmax = fmaxf(tmax, __shfl_xor(tmax, off));
      const float mn = fmaxf(mstate[t4], tmax);
      const float fscl = __expf(mstate[t4] - mn);
      mstate[t4] = mn;
      float psum = 0.f;
      #pragma unroll
      for (int ni = 0; ni < 4; ++ni) {
        float p = __expf(sv[ni] - mn);
        psum += p;
        Ps[grow * 72 + ni * 16 + fr] = f2bf(p);
      }
      #pragma unroll
      for (int off = 1; off < 16; off <<= 1) psum += __shfl_xor(psum, off);
      lstate[t4] = lstate[t4] * fscl + psum;
      #pragma unroll
      for (int ni = 0; ni < 4; ++ni) oacc[ni][t4] *= fscl;
    }

    #pragma unroll
    for (int ks = 0; ks < 2; ++ks) {
      bf16x8 pa = *(const bf16x8*)&Ps[(w * 16 + fr) * 72 + ks * 32 + fg * 8];
      #pragma unroll
      for (int ni = 0; ni < 4; ++ni) {
        bf16x8 vb = *(const bf16x8*)&Vt[(ni * 16 + fr) * 72 + ks * 32 + fg * 8];
        oacc[ni] = __builtin_amdgcn_mfma_f32_16x16x32_bf16(pa, vb, oacc[ni], 0, 0, 0);
      }
    }
  }

  #pragma unroll
  for (int t4 = 0; t4 < 4; ++t4) {
    const int grow = w * 16 + orow + t4;
    const float inv = 1.f / lstate[t4];
    unsigned short* og = vals + (size_t)(b * 64 + grow) * DMODEL + h * 64;
    #pragma unroll
    for (int ni = 0; ni < 4; ++ni)
      og[ni * 16 + fr] = f2bf(oacc[ni][t4] * inv);
  }
}

// ---------------------------------------------------------------------------
// LayerNorm over D=512 (single input; residual pre-added by GEMM epilogue).
// One wave per row, 8 elems/lane. out16 and/or out32.
// ---------------------------------------------------------------------------
__global__ __launch_bounds__(256)
void ln_kernel(const unsigned short* __restrict__ in16,
               const float* __restrict__ gamma, const float* __restrict__ beta,
               unsigned short* __restrict__ out16, float* __restrict__ out32)
{
  const int w = threadIdx.x >> 6, lane = threadIdx.x & 63;
  const size_t r = (size_t)blockIdx.x * 4 + w;
  const int d0 = lane * 8;

  float x[8];
  {
    uint4 u = *(const uint4*)(in16 + r * DMODEL + d0);
    const unsigned short* s = (const unsigned short*)&u;
    #pragma unroll
    for (int j = 0; j < 8; ++j) x[j] = bf2f(s[j]);
  }

  float sum = 0.f;
  #pragma unroll
  for (int j = 0; j < 8; ++j) sum += x[j];
  #pragma unroll
  for (int off = 32; off > 0; off >>= 1) sum += __shfl_xor(sum, off);
  const float mean = sum * (1.f / DMODEL);

  float vs = 0.f;
  #pragma unroll
  for (int j = 0; j < 8; ++j) { float t = x[j] - mean; vs += t * t; }
  #pragma unroll
  for (int off = 32; off > 0; off >>= 1) vs += __shfl_xor(vs, off);
  const float rstd = rsqrtf(vs * (1.f / DMODEL) + 1e-5f);

  float4 g0 = *(const float4*)(gamma + d0), g1 = *(const float4*)(gamma + d0 + 4);
  float4 b0 = *(const float4*)(beta + d0),  b1 = *(const float4*)(beta + d0 + 4);
  const float g[8]  = {g0.x, g0.y, g0.z, g0.w, g1.x, g1.y, g1.z, g1.w};
  const float bb[8] = {b0.x, b0.y, b0.z, b0.w, b1.x, b1.y, b1.z, b1.w};
  float y[8];
  #pragma unroll
  for (int j = 0; j < 8; ++j) y[j] = g[j] * (x[j] - mean) * rstd + bb[j];

  if (out16) {
    union { unsigned short s[8]; uint4 v; } p;
    #pragma unroll
    for (int j = 0; j < 8; ++j) p.s[j] = f2bf(y[j]);
    *(uint4*)(out16 + r * DMODEL + d0) = p.v;
  }
  if (out32) {
    float* o = out32 + r * DMODEL + d0;
    *(float4*)o       = (float4){y[0], y[1], y[2], y[3]};
    *(float4*)(o + 4) = (float4){y[4], y[5], y[6], y[7]};
  }
}

// ---------------------------------------------------------------------------
// Transpose + f32->bf16 convert: W[K,N] f32 -> Wt[N,K] bf16. 32x32 LDS tiles.
// ---------------------------------------------------------------------------
__global__ __launch_bounds__(256)
void transpose_cvt(const float* __restrict__ W, unsigned short* __restrict__ Wt,
                   int K, int N)
{
  __shared__ float tile[32][33];
  const int tx = threadIdx.x, ty = threadIdx.y;
  const int n = blockIdx.x * 32 + tx;
  #pragma unroll
  for (int rr = 0; rr < 4; ++rr) {
    const int k = blockIdx.y * 32 + ty + rr * 8;
    tile[ty + rr * 8][tx] = W[(size_t)k * N + n];
  }
  __syncthreads();
  const int k2 = blockIdx.y * 32 + tx;
  #pragma unroll
  for (int rr = 0; rr < 4; ++rr) {
    const int n2 = blockIdx.x * 32 + ty + rr * 8;
    Wt[(size_t)n2 * K + k2] = f2bf(tile[tx][ty + rr * 8]);
  }
}

// ---------------------------------------------------------------------------
extern "C" void kernel_launch(void* const* d_in, const int* in_sizes, int n_in,
                              void* d_out, int out_size, void* d_ws, size_t ws_size,
                              hipStream_t stream)
{
  const float* x        = (const float*)d_in[0];
  const float* y        = (const float*)d_in[1];
  const float* mask     = (const float*)d_in[2];
  const float* mask2    = (const float*)d_in[3];
  const float* qkv_w    = (const float*)d_in[4];
  const float* qkv_b    = (const float*)d_in[5];
  const float* sa_out_w = (const float*)d_in[6];
  const float* sa_out_b = (const float*)d_in[7];
  const float* q_w      = (const float*)d_in[8];
  const float* q_b      = (const float*)d_in[9];
  const float* kv_w     = (const float*)d_in[10];
  const float* kv_b     = (const float*)d_in[11];
  const float* ca_out_w = (const float*)d_in[12];
  const float* ca_out_b = (const float*)d_in[13];
  const float* l1_w     = (const float*)d_in[14];
  const float* l1_b     = (const float*)d_in[15];
  const float* l2_w     = (const float*)d_in[16];
  const float* l2_b     = (const float*)d_in[17];
  const float* g1 = (const float*)d_in[18];
  const float* b1 = (const float*)d_in[19];
  const float* g2 = (const float*)d_in[20];
  const float* b2 = (const float*)d_in[21];
  const float* g3 = (const float*)d_in[22];
  const float* b3 = (const float*)d_in[23];

  const int B  = in_sizes[1] / (SDEC * DMODEL);   // 256
  const int M  = B * SDEC;                        // 16384 decoder tokens
  const int ME = B * SENC;                        // 131072 encoder tokens

  char* ws = (char*)d_ws;
  size_t off = 0;
  auto alloc = [&](size_t bytes) -> char* {
    char* p = ws + off;
    off += (bytes + 255) & ~(size_t)255;
    return p;
  };
  // persistent regions
  unsigned short* qkv_wt = (unsigned short*)alloc((size_t)1536 * 512 * 2);
  unsigned short* sa_wt  = (unsigned short*)alloc((size_t)512 * 512 * 2);
  unsigned short* q_wt   = (unsigned short*)alloc((size_t)512 * 512 * 2);
  unsigned short* kv_wt  = (unsigned short*)alloc((size_t)1024 * 512 * 2);
  unsigned short* ca_wt  = (unsigned short*)alloc((size_t)512 * 512 * 2);
  unsigned short* l1_wt  = (unsigned short*)alloc((size_t)2048 * 512 * 2);
  unsigned short* l2_wt  = (unsigned short*)alloc((size_t)512 * 2048 * 2);
  unsigned short* kvb    = (unsigned short*)alloc((size_t)ME * 1024 * 2);  // 256 MiB
  char*           xreg   = alloc((size_t)ME * 512 * 2);                    // 128 MiB region
  // xreg aliases (qkvb dead after self-attn):
  unsigned short* qkvb   = (unsigned short*)xreg;                          // 48 MiB
  unsigned short* qb     = (unsigned short*)xreg;                          // 16 MiB (after self-attn)
  unsigned short* y2b    = (unsigned short*)(xreg + (size_t)16777216);     // @16 MiB
  unsigned short* valsb  = (unsigned short*)(xreg + (size_t)50331648);     // @48 MiB
  unsigned short* proj   = (unsigned short*)(xreg + (size_t)67108864);     // @64 MiB (bf16)
  unsigned short* y1b    = (unsigned short*)(xreg + (size_t)100663296);    // @96 MiB
  unsigned short* hb     = kvb;  // FFN hidden aliases kv (kv dead after cross-attn)
  (void)ws_size; (void)n_in; (void)out_size;

  // --- weight transposes (f32 [K,N] -> bf16 [N,K]) ---
  dim3 tb(32, 8);
  transpose_cvt<<<dim3(1536 / 32, 512 / 32), tb, 0, stream>>>(qkv_w, qkv_wt, 512, 1536);
  transpose_cvt<<<dim3(512 / 32, 512 / 32), tb, 0, stream>>>(sa_out_w, sa_wt, 512, 512);
  transpose_cvt<<<dim3(512 / 32, 512 / 32), tb, 0, stream>>>(q_w, q_wt, 512, 512);
  transpose_cvt<<<dim3(1024 / 32, 512 / 32), tb, 0, stream>>>(kv_w, kv_wt, 512, 1024);
  transpose_cvt<<<dim3(512 / 32, 512 / 32), tb, 0, stream>>>(ca_out_w, ca_wt, 512, 512);
  transpose_cvt<<<dim3(2048 / 32, 512 / 32), tb, 0, stream>>>(l1_w, l1_wt, 512, 2048);
  transpose_cvt<<<dim3(512 / 32, 2048 / 32), tb, 0, stream>>>(l2_w, l2_wt, 2048, 512);

  const float scale = 0.125f;  // 1/sqrt(64)

  // --- kv projection: reads x f32 directly (cvt fused into async A-staging) ---
  gemm_kernel<1, 0, 0><<<dim3(1024 / 128, ME / 128), 256, 0, stream>>>(x, kv_wt, kv_b, nullptr, kvb, ME, 1024, 512);

  // --- self attention (qkv reads y f32 directly) ---
  gemm_kernel<1, 0, 0><<<dim3(1536 / 128, M / 128), 256, 0, stream>>>(y, qkv_wt, qkv_b, nullptr, qkvb, M, 1536, 512);
  // qkv row layout per token: head h -> [h*192 .. ): q(64) | k(64) | v(64)
  attn_mfma<<<dim3(8, B), 256, 0, stream>>>(qkvb, 1536, 192, qkvb, 1536, 192, 64, SDEC, SDEC, mask, valsb, scale);
  // sa projection + fused residual (y, f32) -> proj = sa_out + y
  gemm_kernel<0, 0, 1><<<dim3(512 / 128, M / 128), 256, 0, stream>>>(valsb, sa_wt, sa_out_b, y, proj, M, 512, 512);
  ln_kernel<<<M / 4, 256, 0, stream>>>(proj, g1, b1, y1b, nullptr);

  // --- cross attention ---
  gemm_kernel<0, 0, 0><<<dim3(512 / 128, M / 128), 256, 0, stream>>>(y1b, q_wt, q_b, nullptr, qb, M, 512, 512);
  // kv row layout per token: head h -> [h*128 .. ): k(64) | v(64)
  attn_mfma<<<dim3(8, B), 256, 0, stream>>>(qb, 512, 64, kvb, 1024, 128, 0, SENC, SENC, mask2, valsb, scale);
  // ca projection + fused residual (y1b, bf16)
  gemm_kernel<0, 0, 2><<<dim3(512 / 128, M / 128), 256, 0, stream>>>(valsb, ca_wt, ca_out_b, y1b, proj, M, 512, 512);
  ln_kernel<<<M / 4, 256, 0, stream>>>(proj, g2, b2, y2b, nullptr);

  // --- FFN ---
  gemm_kernel<0, 1, 0><<<dim3(2048 / 128, M / 128), 256, 0, stream>>>(y2b, l1_wt, l1_b, nullptr, hb, M, 2048, 512);
  // ffn2 + fused residual (y2b, bf16)
  gemm_kernel<0, 0, 2><<<dim3(512 / 128, M / 128), 256, 0, stream>>>(hb, l2_wt, l2_b, y2b, proj, M, 512, 2048);
  ln_kernel<<<M / 4, 256, 0, stream>>>(proj, g3, b3, nullptr, (float*)d_out);
}